// Round 1
// baseline (4546.426 us; speedup 1.0000x reference)
//
#include <hip/hip_runtime.h>
#include <hip/hip_bf16.h>

#define S 32768
#define BUFN (2*64*32768)

// ---------------- K1: qkv = x @ qkv_w.T, write q,k,v as [B,64,S] ----------------
__global__ __launch_bounds__(256) void k_qkv(const float* __restrict__ x,
    const float* __restrict__ qkv_w, float* __restrict__ q,
    float* __restrict__ k, float* __restrict__ v) {
  __shared__ float wsm[96*64];
  int half = blockIdx.x >> 8;                     // 512 blocks -> 2 halves of rows
  int gid  = ((blockIdx.x & 255) << 8) + threadIdx.x;  // 0..65535 = (b,n)
  int rbase = half * 96;
  for (int i = threadIdx.x; i < 96*64; i += 256) wsm[i] = qkv_w[rbase*64 + i];
  __syncthreads();
  int b = gid >> 15, n = gid & (S-1);
  const float* xr = x + (size_t)gid * 64;
  float xv[64];
#pragma unroll
  for (int i = 0; i < 16; i++) {
    float4 t = ((const float4*)xr)[i];
    xv[4*i]=t.x; xv[4*i+1]=t.y; xv[4*i+2]=t.z; xv[4*i+3]=t.w;
  }
  for (int r = 0; r < 96; r++) {
    float acc = 0.f;
#pragma unroll
    for (int c = 0; c < 64; c++) acc += xv[c] * wsm[r*64+c];
    int row = rbase + r;
    float* dst = (row < 64) ? q : (row < 128 ? k : v);
    int ch = row & 63;
    dst[((size_t)(b*64 + ch))*S + n] = acc;
  }
}

// ---------------- K2: per-row inv L2 norm of q,k (256 rows of 32768) ----------------
__global__ __launch_bounds__(256) void k_rownorm(const float* __restrict__ q,
    const float* __restrict__ k, float* __restrict__ inv) {
  int row = blockIdx.x;                                // 0..255
  const float* p = (row < 128) ? (q + (size_t)row*S) : (k + (size_t)(row-128)*S);
  const float4* p4 = (const float4*)p;
  float ss = 0.f;
  for (int i = threadIdx.x; i < S/4; i += 256) {
    float4 t = p4[i];
    ss += t.x*t.x + t.y*t.y + t.z*t.z + t.w*t.w;
  }
  __shared__ float red[256];
  red[threadIdx.x] = ss; __syncthreads();
  for (int st = 128; st > 0; st >>= 1) {
    if (threadIdx.x < st) red[threadIdx.x] += red[threadIdx.x+st];
    __syncthreads();
  }
  if (threadIdx.x == 0) inv[row] = 1.0f / fmaxf(sqrtf(red[0]), 1e-12f);
}

// ---------------- K3: gram[b,h,c,d] = sum_n q[c,n]k[d,n] (raw, atomic partials) ----
__global__ __launch_bounds__(256) void k_gram(const float* __restrict__ q,
    const float* __restrict__ k, float* __restrict__ gram) {
  __shared__ float qt[16][65], kt[16][65];
  int bi = blockIdx.x;                                 // 256 = b(2)*h(4)*chunk(32)
  int b = bi >> 7, h = (bi >> 5) & 3, chunk = bi & 31;
  int c = threadIdx.x >> 4, d = threadIdx.x & 15;
  const float* qb = q + ((size_t)(b*64 + h*16))*S;
  const float* kb = k + ((size_t)(b*64 + h*16))*S;
  int lr = threadIdx.x >> 4, lc = (threadIdx.x & 15) * 4;
  float acc = 0.f;
  for (int n0 = chunk*1024; n0 < chunk*1024 + 1024; n0 += 64) {
    float4 tq = *(const float4*)(qb + (size_t)lr*S + n0 + lc);
    float4 tk = *(const float4*)(kb + (size_t)lr*S + n0 + lc);
    __syncthreads();
    qt[lr][lc]=tq.x; qt[lr][lc+1]=tq.y; qt[lr][lc+2]=tq.z; qt[lr][lc+3]=tq.w;
    kt[lr][lc]=tk.x; kt[lr][lc+1]=tk.y; kt[lr][lc+2]=tk.z; kt[lr][lc+3]=tk.w;
    __syncthreads();
#pragma unroll
    for (int nn = 0; nn < 64; nn++) acc += qt[c][nn]*kt[d][nn];
  }
  atomicAdd(&gram[((b*4+h)*16+c)*16 + d], acc);
}

// ---------------- K4: softmax over d with inv-norm scaling + temperature ----------
__global__ void k_attnsm(const float* __restrict__ gram, const float* __restrict__ inv,
    const float* __restrict__ temp, float* __restrict__ attn) {
  int t = threadIdx.x; if (t >= 128) return;
  int b = t >> 6, h = (t >> 4) & 3, c = t & 15;
  float iq = inv[b*64 + h*16 + c];
  float tp = temp[h];
  float l[16], m = -1e30f;
#pragma unroll
  for (int d = 0; d < 16; d++) {
    float vv = gram[((b*4+h)*16+c)*16 + d] * iq * inv[128 + b*64 + h*16 + d] * tp;
    l[d] = vv; m = fmaxf(m, vv);
  }
  float s = 0.f;
#pragma unroll
  for (int d = 0; d < 16; d++) { l[d] = expf(l[d]-m); s += l[d]; }
  float is = 1.0f / s;
#pragma unroll
  for (int d = 0; d < 16; d++) attn[((b*4+h)*16+c)*16 + d] = l[d]*is;
}

// ---------------- K5: x_ca = attn@v, layernorm, store x5 [B,64,S] ----------------
__global__ __launch_bounds__(256) void k_xca_ln(const float* __restrict__ v,
    const float* __restrict__ attn, const float* __restrict__ nw,
    const float* __restrict__ nb, float* __restrict__ x5) {
  __shared__ float at[1024];
  __shared__ float wsh[64], bsh[64];
  int gid = blockIdx.x*256 + threadIdx.x;
  int b = gid >> 15, n = gid & (S-1);
  for (int i = threadIdx.x; i < 1024; i += 256) at[i] = attn[b*1024 + i];
  if (threadIdx.x < 64) { wsh[threadIdx.x]=nw[threadIdx.x]; bsh[threadIdx.x]=nb[threadIdx.x]; }
  __syncthreads();
  const float* vb = v + (size_t)b*64*S + n;
  float vv[64];
#pragma unroll
  for (int ch = 0; ch < 64; ch++) vv[ch] = vb[(size_t)ch*S];
  float xc[64];
#pragma unroll
  for (int h = 0; h < 4; h++)
#pragma unroll
    for (int cc = 0; cc < 16; cc++) {
      float a = 0.f;
#pragma unroll
      for (int d = 0; d < 16; d++) a += at[(h*16+cc)*16 + d] * vv[h*16+d];
      xc[h*16+cc] = a;
    }
  float mean = 0.f;
#pragma unroll
  for (int ch = 0; ch < 64; ch++) mean += xc[ch];
  mean *= (1.0f/64.0f);
  float var = 0.f;
#pragma unroll
  for (int ch = 0; ch < 64; ch++) { float d = xc[ch]-mean; var += d*d; }
  var *= (1.0f/64.0f);
  float rs = rsqrtf(var + 1e-5f);
  float* xb = x5 + (size_t)b*64*S + n;
#pragma unroll
  for (int ch = 0; ch < 64; ch++)
    xb[(size_t)ch*S] = (xc[ch]-mean)*rs*wsh[ch] + bsh[ch];
}

// ---------------- K6: proj1 (1x1) + exact GELU -> u ----------------
__global__ __launch_bounds__(256) void k_proj1(const float* __restrict__ x5,
    const float* __restrict__ w, const float* __restrict__ bias, float* __restrict__ u) {
  __shared__ float wsm[32*64];
  __shared__ float bsm[32];
  int half = blockIdx.x >> 8;
  int gid = ((blockIdx.x & 255) << 8) + threadIdx.x;
  int o0 = half*32;
  for (int i = threadIdx.x; i < 32*64; i += 256) wsm[i] = w[o0*64 + i];
  if (threadIdx.x < 32) bsm[threadIdx.x] = bias[o0 + threadIdx.x];
  __syncthreads();
  int b = gid >> 15, n = gid & (S-1);
  const float* xb = x5 + (size_t)b*64*S + n;
  float xv[64];
#pragma unroll
  for (int ch = 0; ch < 64; ch++) xv[ch] = xb[(size_t)ch*S];
  float* ub = u + (size_t)b*64*S + n;
  for (int oo = 0; oo < 32; oo++) {
    float acc = bsm[oo];
#pragma unroll
    for (int c = 0; c < 64; c++) acc += wsm[oo*64+c]*xv[c];
    float g = 0.5f*acc*(1.0f + erff(acc*0.70710678118654752f));
    ub[(size_t)(o0+oo)*S] = g;
  }
}

// ---------------- K7: depthwise conv 5^3 pad 2 ----------------
__global__ __launch_bounds__(256) void k_conv0(const float* __restrict__ in,
    const float* __restrict__ w, const float* __restrict__ bias, float* __restrict__ out) {
  __shared__ float tile[12*1024];
  __shared__ float wsh[125];
  int bi = blockIdx.x;                    // 512 = b(2)*c(64)*zs(4)
  int zs = bi & 3, c = (bi >> 2) & 63, b = bi >> 8;
  int z0 = zs*8;
  const float* ib = in + ((size_t)(b*64+c))*S;
  for (int i = threadIdx.x; i < 12*1024; i += 256) {
    int zz = i >> 10, rest = i & 1023;
    int zg = z0 - 2 + zz;
    tile[i] = (zg >= 0 && zg < 32) ? ib[zg*1024 + rest] : 0.f;
  }
  if (threadIdx.x < 125) wsh[threadIdx.x] = w[c*125 + threadIdx.x];
  __syncthreads();
  float bv = bias[c];
  int x = threadIdx.x & 31, y0 = threadIdx.x >> 5;
  float* ob = out + ((size_t)(b*64+c))*S;
  for (int zi = 0; zi < 8; zi++) {
    for (int yj = 0; yj < 4; yj++) {
      int y = y0 + yj*8;
      float acc = bv;
      for (int dz = 0; dz < 5; dz++)
        for (int dy = 0; dy < 5; dy++) {
          int yy = y + dy - 2; if (yy < 0 || yy >= 32) continue;
          const float* tr = &tile[(zi+dz)*1024 + yy*32];
#pragma unroll
          for (int dx = 0; dx < 5; dx++) {
            int xx = x + dx - 2;
            if (xx >= 0 && xx < 32) acc += wsh[(dz*5+dy)*5+dx]*tr[xx];
          }
        }
      ob[(z0+zi)*1024 + y*32 + x] = acc;
    }
  }
}

// ---------------- K8: depthwise conv 7^3 dil 3 pad 9 ----------------
__global__ __launch_bounds__(256) void k_convsp(const float* __restrict__ in,
    const float* __restrict__ w, const float* __restrict__ bias, float* __restrict__ out) {
  __shared__ float tile[7*1024];
  __shared__ float wsh[343];
  int bi = blockIdx.x;                    // 4096 = b(2)*c(64)*z(32)
  int z = bi & 31, c = (bi >> 5) & 63, b = bi >> 11;
  const float* ib = in + ((size_t)(b*64+c))*S;
  for (int i = threadIdx.x; i < 7*1024; i += 256) {
    int t = i >> 10, rest = i & 1023;
    int zg = z + 3*t - 9;
    tile[i] = (zg >= 0 && zg < 32) ? ib[zg*1024 + rest] : 0.f;
  }
  for (int i = threadIdx.x; i < 343; i += 256) wsh[i] = w[c*343 + i];
  __syncthreads();
  int x = threadIdx.x & 31, y0 = threadIdx.x >> 5;
  float bv = bias[c];
  float* ob = out + ((size_t)(b*64+c))*S + z*1024;
  for (int yj = 0; yj < 4; yj++) {
    int y = y0 + yj*8;
    float acc = bv;
    for (int t = 0; t < 7; t++)
      for (int dy = 0; dy < 7; dy++) {
        int yy = y + 3*dy - 9; if (yy < 0 || yy >= 32) continue;
        const float* tr = &tile[t*1024 + yy*32];
#pragma unroll
        for (int dx = 0; dx < 7; dx++) {
          int xx = x + 3*dx - 9;
          if (xx >= 0 && xx < 32) acc += wsh[(t*7+dy)*7+dx]*tr[xx];
        }
      }
    ob[y*32+x] = acc;
  }
}

// ---------------- K9: offsets conv (81 out ch, 3^3 pad 1), split by dz, atomic ----
__global__ __launch_bounds__(256) void k_offconv(const float* __restrict__ a2,
    const float* __restrict__ ow, float* __restrict__ off) {
  __shared__ float tin[3*64*34];          // dy, c, x(-1..32)
  int bi = blockIdx.x;                    // 6144 = b(2)*zy(1024)*kg(3)
  int kg = bi % 3;
  int zy = (bi/3) & 1023;
  int b  = bi / 3072;
  int z = zy >> 5, y = zy & 31;
  int zz = z + kg - 1;
  bool zok = (zz >= 0 && zz < 32);
  for (int i = threadIdx.x; i < 3*64*34; i += 256) {
    int dy = i / (64*34); int rem = i % (64*34); int c = rem / 34; int xx = rem % 34;
    int yy = y + dy - 1; int xg = xx - 1;
    float val = 0.f;
    if (zok && yy >= 0 && yy < 32 && xg >= 0 && xg < 32)
      val = a2[((size_t)(b*64+c))*S + zz*1024 + yy*32 + xg];
    tin[i] = val;
  }
  __syncthreads();
  if (!zok) return;
  int xl = threadIdx.x & 15, og = threadIdx.x >> 4;
  float acc[6][2];
#pragma unroll
  for (int j = 0; j < 6; j++) { acc[j][0]=0.f; acc[j][1]=0.f; }
  int jmax = (og == 0) ? 6 : 5;
  for (int dy = 0; dy < 3; dy++) {
    for (int c = 0; c < 64; c++) {
      const float* tr = &tin[(dy*64 + c)*34];
      float t0a = tr[xl],    t1a = tr[xl+1],  t2a = tr[xl+2];
      float t0b = tr[xl+16], t1b = tr[xl+17], t2b = tr[xl+18];
      const float* wb = ow + (size_t)og*1728 + c*27 + kg*9 + dy*3;
      for (int j = 0; j < jmax; j++) {
        const float* wj = wb + (size_t)j*16*1728;
        float w0 = wj[0], w1 = wj[1], w2 = wj[2];
        acc[j][0] += w0*t0a + w1*t1a + w2*t2a;
        acc[j][1] += w0*t0b + w1*t1b + w2*t2b;
      }
    }
  }
  size_t obase = (size_t)b*81*S + (size_t)z*1024 + y*32;
  for (int j = 0; j < jmax; j++) {
    int o = og + 16*j;
    atomicAdd(&off[obase + (size_t)o*S + xl],      acc[j][0]);
    atomicAdd(&off[obase + (size_t)o*S + xl + 16], acc[j][1]);
  }
}

// ---------------- K10: deformable conv (gather + 64x64x27 einsum), kg split ------
__global__ __launch_bounds__(256) void k_dcn(const float* __restrict__ a2,
    const float* __restrict__ off, const float* __restrict__ off_b,
    const float* __restrict__ dcn_w, float* __restrict__ out) {
  __shared__ float cw[8][32];
  __shared__ int   cidx[8][32];
  __shared__ float samp[64*33];
  __shared__ float wsh[64*65];
  int bi = blockIdx.x;                    // 6144 = b(2)*sc(1024)*kg(3)
  int kg = bi % 3; int sc = (bi/3) & 1023; int b = bi / 3072;
  int s0 = sc * 32;
  int tid = threadIdx.x;
  float acc[4][2];
#pragma unroll
  for (int j = 0; j < 4; j++) { acc[j][0]=0.f; acc[j][1]=0.f; }
  const float* a2b = a2 + (size_t)b*64*S;
  for (int t = 0; t < 9; t++) {
    int k = kg*9 + t;
    __syncthreads();
    for (int i = tid; i < 4096; i += 256)
      wsh[(i>>6)*65 + (i&63)] = dcn_w[(size_t)i*27 + k];
    if (tid < 32) {
      int s = s0 + tid;
      int z = s >> 10, yy = (s >> 5) & 31, x = s & 31;
      int kz = kg, ky = (k/3)%3, kx = k%3;
      float pz = (float)(z + kz - 1) + off[((size_t)(b*81) + 3*k+0)*S + s] + off_b[3*k+0];
      float py = (float)(yy + ky - 1) + off[((size_t)(b*81) + 3*k+1)*S + s] + off_b[3*k+1];
      float px = (float)(x + kx - 1) + off[((size_t)(b*81) + 3*k+2)*S + s] + off_b[3*k+2];
      float fz = floorf(pz), fy = floorf(py), fx = floorf(px);
      float wz = pz-fz, wy = py-fy, wx = px-fx;
      int z0 = (int)fz, y0 = (int)fy, x0 = (int)fx;
#pragma unroll
      for (int r = 0; r < 8; r++) {
        int dz = r>>2, dy = (r>>1)&1, dx = r&1;
        int iz = z0+dz, iy = y0+dy, ix = x0+dx;
        bool valid = (iz>=0 && iz<32 && iy>=0 && iy<32 && ix>=0 && ix<32);
        float cwv = (dz?wz:1.f-wz)*(dy?wy:1.f-wy)*(dx?wx:1.f-wx);
        cw[r][tid] = valid ? cwv : 0.f;
        int czi = min(max(iz,0),31), cyi = min(max(iy,0),31), cxi = min(max(ix,0),31);
        cidx[r][tid] = czi*1024 + cyi*32 + cxi;
      }
    }
    __syncthreads();
    {
      int c = tid >> 2;
      int sbase = (tid & 3) * 8;
      const float* ab = a2b + (size_t)c*S;
#pragma unroll
      for (int i = 0; i < 8; i++) {
        int sl = sbase + i;
        float sv = 0.f;
#pragma unroll
        for (int r = 0; r < 8; r++) sv += cw[r][sl] * ab[cidx[r][sl]];
        samp[c*33 + sl] = sv;
      }
    }
    __syncthreads();
    {
      int sl = tid & 15, og = tid >> 4;
      for (int c = 0; c < 64; c++) {
        float v0 = samp[c*33 + sl], v1 = samp[c*33 + sl + 16];
#pragma unroll
        for (int j = 0; j < 4; j++) {
          float wv = wsh[(og + 16*j)*65 + c];
          acc[j][0] += wv*v0; acc[j][1] += wv*v1;
        }
      }
    }
  }
  int sl = tid & 15, og = tid >> 4;
  for (int j = 0; j < 4; j++) {
    int o = og + 16*j;
    atomicAdd(&out[((size_t)(b*64+o))*S + s0 + sl],      acc[j][0]);
    atomicAdd(&out[((size_t)(b*64+o))*S + s0 + sl + 16], acc[j][1]);
  }
}

// ---------------- K11: conv1(+dcn_b) -> gate with u -> proj2 + shortcut ----------
__global__ __launch_bounds__(256) void k_fuse2(const float* __restrict__ dcn,
    const float* __restrict__ dcn_b, const float* __restrict__ c1w,
    const float* __restrict__ c1b, const float* __restrict__ u,
    const float* __restrict__ p2w, const float* __restrict__ p2b,
    const float* __restrict__ x5, float* __restrict__ y2) {
  __shared__ float w1[4096], w2[4096];
  __shared__ float b1[64], b2[64], db[64];
  int gid = blockIdx.x*256 + threadIdx.x;
  for (int i = threadIdx.x; i < 4096; i += 256) { w1[i] = c1w[i]; w2[i] = p2w[i]; }
  if (threadIdx.x < 64) {
    b1[threadIdx.x]=c1b[threadIdx.x]; b2[threadIdx.x]=p2b[threadIdx.x];
    db[threadIdx.x]=dcn_b[threadIdx.x];
  }
  __syncthreads();
  int b = gid >> 15, n = gid & (S-1);
  const float* dbp = dcn + (size_t)b*64*S + n;
  float dv[64];
#pragma unroll
  for (int c = 0; c < 64; c++) dv[c] = dbp[(size_t)c*S] + db[c];
  const float* ub = u + (size_t)b*64*S + n;
  float m[64];
  for (int o = 0; o < 64; o++) {
    float a = b1[o];
#pragma unroll
    for (int c = 0; c < 64; c++) a += w1[o*64+c]*dv[c];
    m[o] = ub[(size_t)o*S] * a;
  }
  const float* sb = x5 + (size_t)b*64*S + n;
  float* yb = y2 + (size_t)b*64*S + n;
  for (int o = 0; o < 64; o++) {
    float a = b2[o];
#pragma unroll
    for (int c = 0; c < 64; c++) a += w2[o*64+c]*m[c];
    yb[(size_t)o*S] = a + sb[(size_t)o*S];
  }
}

// ---------------- K12: faithful reshape-scramble + LN2 + out proj ----------------
// x_sa[b,n,c] = y2[b, n%64, c*512 + n/64]
__global__ __launch_bounds__(256) void k_final(const float* __restrict__ y2,
    const float* __restrict__ n2w, const float* __restrict__ n2b,
    const float* __restrict__ ow, const float* __restrict__ ob, float* __restrict__ out) {
  __shared__ float wsh[4096];
  __shared__ float nw[64], nb[64], obs[64];
  int bi = blockIdx.x;                    // 256 = b(2)*mg(8)*rg4(16)
  int b = bi >> 7; int mg = (bi >> 4) & 7; int r0 = (bi & 15)*4;
  for (int i = threadIdx.x; i < 4096; i += 256) wsh[i] = ow[i];
  if (threadIdx.x < 64) {
    nw[threadIdx.x]=n2w[threadIdx.x]; nb[threadIdx.x]=n2b[threadIdx.x];
    obs[threadIdx.x]=ob[threadIdx.x];
  }
  __syncthreads();
  int mi = threadIdx.x & 63, rg = threadIdx.x >> 6;
  int r = r0 + rg;
  int m = mg*64 + mi;
  int n = m*64 + r;
  const float* yb = y2 + ((size_t)(b*64+r))*S + m;
  float v[64];
#pragma unroll
  for (int c = 0; c < 64; c++) v[c] = yb[(size_t)c*512];
  float mean = 0.f;
#pragma unroll
  for (int c = 0; c < 64; c++) mean += v[c];
  mean *= (1.0f/64.0f);
  float var = 0.f;
#pragma unroll
  for (int c = 0; c < 64; c++) { float d = v[c]-mean; var += d*d; }
  var *= (1.0f/64.0f);
  float rs = rsqrtf(var + 1e-5f);
#pragma unroll
  for (int c = 0; c < 64; c++) v[c] = (v[c]-mean)*rs*nw[c] + nb[c];
  float* orow = out + ((size_t)b*S + n)*64;
  for (int o4 = 0; o4 < 16; o4++) {
    float4 a;
    float t0=obs[o4*4+0], t1=obs[o4*4+1], t2=obs[o4*4+2], t3=obs[o4*4+3];
#pragma unroll
    for (int c = 0; c < 64; c++) {
      float lv = v[c];
      t0 += wsh[(o4*4+0)*64+c]*lv; t1 += wsh[(o4*4+1)*64+c]*lv;
      t2 += wsh[(o4*4+2)*64+c]*lv; t3 += wsh[(o4*4+3)*64+c]*lv;
    }
    a.x=t0; a.y=t1; a.z=t2; a.w=t3;
    ((float4*)orow)[o4] = a;
  }
}

extern "C" void kernel_launch(void* const* d_in, const int* in_sizes, int n_in,
                              void* d_out, int out_size, void* d_ws, size_t ws_size,
                              hipStream_t stream) {
  const float* x      = (const float*)d_in[0];
  const float* temp   = (const float*)d_in[1];
  const float* qkv_w  = (const float*)d_in[2];
  const float* norm_w = (const float*)d_in[3];
  const float* norm_b = (const float*)d_in[4];
  const float* p1w    = (const float*)d_in[5];
  const float* p1b    = (const float*)d_in[6];
  const float* c0w    = (const float*)d_in[7];
  const float* c0b    = (const float*)d_in[8];
  const float* cspw   = (const float*)d_in[9];
  const float* cspb   = (const float*)d_in[10];
  const float* offw   = (const float*)d_in[11];
  const float* offb   = (const float*)d_in[12];
  const float* dcnw   = (const float*)d_in[13];
  const float* dcnb   = (const float*)d_in[14];
  const float* c1w    = (const float*)d_in[15];
  const float* c1b    = (const float*)d_in[16];
  const float* p2w    = (const float*)d_in[17];
  const float* p2b    = (const float*)d_in[18];
  const float* n2w    = (const float*)d_in[19];
  const float* n2b    = (const float*)d_in[20];
  const float* outw   = (const float*)d_in[21];
  const float* outb   = (const float*)d_in[22];
  float* out = (float*)d_out;

  float* Wa  = (float*)d_ws;                  // q -> x5
  float* Wb  = Wa + BUFN;                     // k -> u
  float* Wc  = Wb + BUFN;                     // a2 -> y2
  float* OFF = Wc + BUFN;                     // 2*81*32768 floats
  float* SM  = OFF + (size_t)2*81*S;          // small: inv[256], gram[2048], attn[2048]
  float* SM_inv  = SM;
  float* SM_gram = SM + 256;
  float* SM_attn = SM + 2304;
  float* vbuf = out;                          // d_out doubles as scratch: v -> a1 -> dcn

  hipMemsetAsync(SM, 0, 4352*sizeof(float), stream);

  k_qkv    <<<512, 256, 0, stream>>>(x, qkv_w, Wa, Wb, vbuf);
  k_rownorm<<<256, 256, 0, stream>>>(Wa, Wb, SM_inv);
  k_gram   <<<256, 256, 0, stream>>>(Wa, Wb, SM_gram);
  k_attnsm <<<1,   128, 0, stream>>>(SM_gram, SM_inv, temp, SM_attn);
  k_xca_ln <<<256, 256, 0, stream>>>(vbuf, SM_attn, norm_w, norm_b, Wa);   // x5 -> Wa
  k_proj1  <<<512, 256, 0, stream>>>(Wa, p1w, p1b, Wb);                    // u -> Wb
  k_conv0  <<<512, 256, 0, stream>>>(Wb, c0w, c0b, vbuf);                  // a1 -> d_out
  k_convsp <<<4096,256, 0, stream>>>(vbuf, cspw, cspb, Wc);                // a2 -> Wc
  hipMemsetAsync(OFF, 0, (size_t)2*81*S*sizeof(float), stream);
  k_offconv<<<6144,256, 0, stream>>>(Wc, offw, OFF);
  hipMemsetAsync(vbuf, 0, (size_t)BUFN*sizeof(float), stream);
  k_dcn    <<<6144,256, 0, stream>>>(Wc, OFF, offb, dcnw, vbuf);           // dcn -> d_out
  k_fuse2  <<<256, 256, 0, stream>>>(vbuf, dcnb, c1w, c1b, Wb, p2w, p2b, Wa, Wc); // y2 -> Wc
  k_final  <<<256, 256, 0, stream>>>(Wc, n2w, n2b, outw, outb, out);
}

// Round 2
// 2408.712 us; speedup vs baseline: 1.8875x; 1.8875x over previous
//
#include <hip/hip_runtime.h>
#include <hip/hip_bf16.h>

#define S 32768
#define BUFN (2*64*32768)

// ---------------- K0: weight transposes (one-off, tiny) ----------------
// wt_off[(t*64+c)*81 + o] = offw[o*1728 + c*27 + t]    (139968)
// wt_dcn[(k*64+c)*64 + o] = dcnw[(o*64+c)*27 + k]      (110592)
__global__ void k_wt(const float* __restrict__ offw, const float* __restrict__ dcnw,
                     float* __restrict__ wt_off, float* __restrict__ wt_dcn) {
  int i = blockIdx.x*256 + threadIdx.x;
  if (i < 139968) {
    int o = i % 81, c = (i/81) & 63, t = i / 5184;
    wt_off[i] = offw[o*1728 + c*27 + t];
  }
  if (i < 110592) {
    int o = i & 63, c = (i >> 6) & 63, k = i >> 12;
    wt_dcn[i] = dcnw[(o*64 + c)*27 + k];
  }
}

// ---------------- K1: qkv = x @ qkv_w.T, write q,k,v as [B,64,S] ----------------
__global__ __launch_bounds__(256) void k_qkv(const float* __restrict__ x,
    const float* __restrict__ qkv_w, float* __restrict__ q,
    float* __restrict__ k, float* __restrict__ v) {
  __shared__ float wsm[96*64];
  int half = blockIdx.x >> 8;
  int gid  = ((blockIdx.x & 255) << 8) + threadIdx.x;
  int rbase = half * 96;
  for (int i = threadIdx.x; i < 96*64; i += 256) wsm[i] = qkv_w[rbase*64 + i];
  __syncthreads();
  int b = gid >> 15, n = gid & (S-1);
  const float* xr = x + (size_t)gid * 64;
  float xv[64];
#pragma unroll
  for (int i = 0; i < 16; i++) {
    float4 t = ((const float4*)xr)[i];
    xv[4*i]=t.x; xv[4*i+1]=t.y; xv[4*i+2]=t.z; xv[4*i+3]=t.w;
  }
  for (int r = 0; r < 96; r++) {
    float acc = 0.f;
#pragma unroll
    for (int c = 0; c < 64; c++) acc += xv[c] * wsm[r*64+c];
    int row = rbase + r;
    float* dst = (row < 64) ? q : (row < 128 ? k : v);
    int ch = row & 63;
    dst[((size_t)(b*64 + ch))*S + n] = acc;
  }
}

// ---------------- K2: per-row inv L2 norm of q,k ----------------
__global__ __launch_bounds__(256) void k_rownorm(const float* __restrict__ q,
    const float* __restrict__ k, float* __restrict__ inv) {
  int row = blockIdx.x;
  const float* p = (row < 128) ? (q + (size_t)row*S) : (k + (size_t)(row-128)*S);
  const float4* p4 = (const float4*)p;
  float ss = 0.f;
  for (int i = threadIdx.x; i < S/4; i += 256) {
    float4 t = p4[i];
    ss += t.x*t.x + t.y*t.y + t.z*t.z + t.w*t.w;
  }
  __shared__ float red[256];
  red[threadIdx.x] = ss; __syncthreads();
  for (int st = 128; st > 0; st >>= 1) {
    if (threadIdx.x < st) red[threadIdx.x] += red[threadIdx.x+st];
    __syncthreads();
  }
  if (threadIdx.x == 0) inv[row] = 1.0f / fmaxf(sqrtf(red[0]), 1e-12f);
}

// ---------------- K3: gram ----------------
__global__ __launch_bounds__(256) void k_gram(const float* __restrict__ q,
    const float* __restrict__ k, float* __restrict__ gram) {
  __shared__ float qt[16][65], kt[16][65];
  int bi = blockIdx.x;
  int b = bi >> 7, h = (bi >> 5) & 3, chunk = bi & 31;
  int c = threadIdx.x >> 4, d = threadIdx.x & 15;
  const float* qb = q + ((size_t)(b*64 + h*16))*S;
  const float* kb = k + ((size_t)(b*64 + h*16))*S;
  int lr = threadIdx.x >> 4, lc = (threadIdx.x & 15) * 4;
  float acc = 0.f;
  for (int n0 = chunk*1024; n0 < chunk*1024 + 1024; n0 += 64) {
    float4 tq = *(const float4*)(qb + (size_t)lr*S + n0 + lc);
    float4 tk = *(const float4*)(kb + (size_t)lr*S + n0 + lc);
    __syncthreads();
    qt[lr][lc]=tq.x; qt[lr][lc+1]=tq.y; qt[lr][lc+2]=tq.z; qt[lr][lc+3]=tq.w;
    kt[lr][lc]=tk.x; kt[lr][lc+1]=tk.y; kt[lr][lc+2]=tk.z; kt[lr][lc+3]=tk.w;
    __syncthreads();
#pragma unroll
    for (int nn = 0; nn < 64; nn++) acc += qt[c][nn]*kt[d][nn];
  }
  atomicAdd(&gram[((b*4+h)*16+c)*16 + d], acc);
}

// ---------------- K4: softmax ----------------
__global__ void k_attnsm(const float* __restrict__ gram, const float* __restrict__ inv,
    const float* __restrict__ temp, float* __restrict__ attn) {
  int t = threadIdx.x; if (t >= 128) return;
  int b = t >> 6, h = (t >> 4) & 3, c = t & 15;
  float iq = inv[b*64 + h*16 + c];
  float tp = temp[h];
  float l[16], m = -1e30f;
#pragma unroll
  for (int d = 0; d < 16; d++) {
    float vv = gram[((b*4+h)*16+c)*16 + d] * iq * inv[128 + b*64 + h*16 + d] * tp;
    l[d] = vv; m = fmaxf(m, vv);
  }
  float s = 0.f;
#pragma unroll
  for (int d = 0; d < 16; d++) { l[d] = expf(l[d]-m); s += l[d]; }
  float is = 1.0f / s;
#pragma unroll
  for (int d = 0; d < 16; d++) attn[((b*4+h)*16+c)*16 + d] = l[d]*is;
}

// ---------------- K5: x_ca = attn@v, layernorm, store x5 ----------------
__global__ __launch_bounds__(256) void k_xca_ln(const float* __restrict__ v,
    const float* __restrict__ attn, const float* __restrict__ nw,
    const float* __restrict__ nb, float* __restrict__ x5) {
  __shared__ float at[1024];
  __shared__ float wsh[64], bsh[64];
  int gid = blockIdx.x*256 + threadIdx.x;
  int b = gid >> 15, n = gid & (S-1);
  for (int i = threadIdx.x; i < 1024; i += 256) at[i] = attn[b*1024 + i];
  if (threadIdx.x < 64) { wsh[threadIdx.x]=nw[threadIdx.x]; bsh[threadIdx.x]=nb[threadIdx.x]; }
  __syncthreads();
  const float* vb = v + (size_t)b*64*S + n;
  float vv[64];
#pragma unroll
  for (int ch = 0; ch < 64; ch++) vv[ch] = vb[(size_t)ch*S];
  float xc[64];
#pragma unroll
  for (int h = 0; h < 4; h++)
#pragma unroll
    for (int cc = 0; cc < 16; cc++) {
      float a = 0.f;
#pragma unroll
      for (int d = 0; d < 16; d++) a += at[(h*16+cc)*16 + d] * vv[h*16+d];
      xc[h*16+cc] = a;
    }
  float mean = 0.f;
#pragma unroll
  for (int ch = 0; ch < 64; ch++) mean += xc[ch];
  mean *= (1.0f/64.0f);
  float var = 0.f;
#pragma unroll
  for (int ch = 0; ch < 64; ch++) { float d = xc[ch]-mean; var += d*d; }
  var *= (1.0f/64.0f);
  float rs = rsqrtf(var + 1e-5f);
  float* xb = x5 + (size_t)b*64*S + n;
#pragma unroll
  for (int ch = 0; ch < 64; ch++)
    xb[(size_t)ch*S] = (xc[ch]-mean)*rs*wsh[ch] + bsh[ch];
}

// ---------------- K6: proj1 + GELU ----------------
__global__ __launch_bounds__(256) void k_proj1(const float* __restrict__ x5,
    const float* __restrict__ w, const float* __restrict__ bias, float* __restrict__ u) {
  __shared__ float wsm[32*64];
  __shared__ float bsm[32];
  int half = blockIdx.x >> 8;
  int gid = ((blockIdx.x & 255) << 8) + threadIdx.x;
  int o0 = half*32;
  for (int i = threadIdx.x; i < 32*64; i += 256) wsm[i] = w[o0*64 + i];
  if (threadIdx.x < 32) bsm[threadIdx.x] = bias[o0 + threadIdx.x];
  __syncthreads();
  int b = gid >> 15, n = gid & (S-1);
  const float* xb = x5 + (size_t)b*64*S + n;
  float xv[64];
#pragma unroll
  for (int ch = 0; ch < 64; ch++) xv[ch] = xb[(size_t)ch*S];
  float* ub = u + (size_t)b*64*S + n;
  for (int oo = 0; oo < 32; oo++) {
    float acc = bsm[oo];
#pragma unroll
    for (int c = 0; c < 64; c++) acc += wsm[oo*64+c]*xv[c];
    float g = 0.5f*acc*(1.0f + erff(acc*0.70710678118654752f));
    ub[(size_t)(o0+oo)*S] = g;
  }
}

// ---------------- K7: depthwise conv 5^3 pad 2 ----------------
__global__ __launch_bounds__(256) void k_conv0(const float* __restrict__ in,
    const float* __restrict__ w, const float* __restrict__ bias, float* __restrict__ out) {
  __shared__ float tile[12*1024];
  __shared__ float wsh[125];
  int bi = blockIdx.x;
  int zs = bi & 3, c = (bi >> 2) & 63, b = bi >> 8;
  int z0 = zs*8;
  const float* ib = in + ((size_t)(b*64+c))*S;
  for (int i = threadIdx.x; i < 12*1024; i += 256) {
    int zz = i >> 10, rest = i & 1023;
    int zg = z0 - 2 + zz;
    tile[i] = (zg >= 0 && zg < 32) ? ib[zg*1024 + rest] : 0.f;
  }
  if (threadIdx.x < 125) wsh[threadIdx.x] = w[c*125 + threadIdx.x];
  __syncthreads();
  float bv = bias[c];
  int x = threadIdx.x & 31, y0 = threadIdx.x >> 5;
  float* ob = out + ((size_t)(b*64+c))*S;
  for (int zi = 0; zi < 8; zi++) {
    for (int yj = 0; yj < 4; yj++) {
      int y = y0 + yj*8;
      float acc = bv;
      for (int dz = 0; dz < 5; dz++)
        for (int dy = 0; dy < 5; dy++) {
          int yy = y + dy - 2; if (yy < 0 || yy >= 32) continue;
          const float* tr = &tile[(zi+dz)*1024 + yy*32];
#pragma unroll
          for (int dx = 0; dx < 5; dx++) {
            int xx = x + dx - 2;
            if (xx >= 0 && xx < 32) acc += wsh[(dz*5+dy)*5+dx]*tr[xx];
          }
        }
      ob[(z0+zi)*1024 + y*32 + x] = acc;
    }
  }
}

// ---------------- K8: depthwise conv 7^3 dil 3 pad 9 ----------------
__global__ __launch_bounds__(256) void k_convsp(const float* __restrict__ in,
    const float* __restrict__ w, const float* __restrict__ bias, float* __restrict__ out) {
  __shared__ float tile[7*1024];
  __shared__ float wsh[343];
  int bi = blockIdx.x;
  int z = bi & 31, c = (bi >> 5) & 63, b = bi >> 11;
  const float* ib = in + ((size_t)(b*64+c))*S;
  for (int i = threadIdx.x; i < 7*1024; i += 256) {
    int t = i >> 10, rest = i & 1023;
    int zg = z + 3*t - 9;
    tile[i] = (zg >= 0 && zg < 32) ? ib[zg*1024 + rest] : 0.f;
  }
  for (int i = threadIdx.x; i < 343; i += 256) wsh[i] = w[c*343 + i];
  __syncthreads();
  int x = threadIdx.x & 31, y0 = threadIdx.x >> 5;
  float bv = bias[c];
  float* ob = out + ((size_t)(b*64+c))*S + z*1024;
  for (int yj = 0; yj < 4; yj++) {
    int y = y0 + yj*8;
    float acc = bv;
    for (int t = 0; t < 7; t++)
      for (int dy = 0; dy < 7; dy++) {
        int yy = y + 3*dy - 9; if (yy < 0 || yy >= 32) continue;
        const float* tr = &tile[t*1024 + yy*32];
#pragma unroll
        for (int dx = 0; dx < 7; dx++) {
          int xx = x + 3*dx - 9;
          if (xx >= 0 && xx < 32) acc += wsh[(t*7+dy)*7+dx]*tr[xx];
        }
      }
    ob[y*32+x] = acc;
  }
}

// ---------------- K9 (NEW): offset conv as register-blocked GEMM ----------------
// Grid: 512 = b(2) * s-tile(256 of 128). Block 256 = og(4, =wave) x sp(64).
// Thread: 21 outputs (o = og*21+j) x 2 s (sp, sp+64). Weights per tap in LDS,
// b128-aligned padded layout wsh[c*96 + og*24 + j]; zero-padded beyond o=80.
__global__ __launch_bounds__(256) void k_offconv(const float* __restrict__ a2,
    const float* __restrict__ wt, float* __restrict__ off) {
  __shared__ float wsh[64*96];            // 24.6 KB
  int bi = blockIdx.x;
  int b = bi >> 8, tile = bi & 255;
  int s0 = tile << 7;                     // 128 s per block, fixed z slice
  int tid = threadIdx.x;
  int og = tid >> 6, sp = tid & 63;
  int sa = s0 + sp, sb = sa + 64;
  int z  = s0 >> 10;
  int ya = (sa >> 5) & 31, xa = sa & 31;
  int yb = (sb >> 5) & 31, xb = sb & 31;
  float accA[21], accB[21];
#pragma unroll
  for (int j = 0; j < 21; j++) { accA[j] = 0.f; accB[j] = 0.f; }
  const float* a2b = a2 + ((size_t)b << 21);
  for (int t = 0; t < 27; t++) {
    int kz = t/9, ky = (t/3)%3, kx = t%3;
    __syncthreads();
    for (int i = tid; i < 6144; i += 256) {
      int c = i/96, r = i%96, qt = r/24, j = r%24;
      int o = qt*21 + j;
      wsh[i] = (j < 21 && o < 81) ? wt[(t*64 + c)*81 + o] : 0.f;
    }
    __syncthreads();
    int zz = z + kz - 1;
    int yya = ya + ky - 1, xxa = xa + kx - 1;
    int yyb = yb + ky - 1, xxb = xb + kx - 1;
    bool va = (zz>=0 && zz<32 && yya>=0 && yya<32 && xxa>=0 && xxa<32);
    bool vb = (zz>=0 && zz<32 && yyb>=0 && yyb<32 && xxb>=0 && xxb<32);
    int ia = zz*1024 + yya*32 + xxa;
    int ib = zz*1024 + yyb*32 + xxb;
#pragma unroll 8
    for (int c = 0; c < 64; c++) {
      const float* base = a2b + ((size_t)c << 15);
      float vA = va ? base[ia] : 0.f;
      float vB = vb ? base[ib] : 0.f;
      const float* wq = &wsh[c*96 + og*24];
      float4 w0 = ((const float4*)wq)[0];
      float4 w1 = ((const float4*)wq)[1];
      float4 w2 = ((const float4*)wq)[2];
      float4 w3 = ((const float4*)wq)[3];
      float4 w4 = ((const float4*)wq)[4];
      float4 w5 = ((const float4*)wq)[5];
      float wr[24] = {w0.x,w0.y,w0.z,w0.w, w1.x,w1.y,w1.z,w1.w,
                      w2.x,w2.y,w2.z,w2.w, w3.x,w3.y,w3.z,w3.w,
                      w4.x,w4.y,w4.z,w4.w, w5.x,w5.y,w5.z,w5.w};
#pragma unroll
      for (int j = 0; j < 21; j++) {
        accA[j] += wr[j]*vA;
        accB[j] += wr[j]*vB;
      }
    }
  }
#pragma unroll
  for (int j = 0; j < 21; j++) {
    int o = og*21 + j;
    if (o < 81) {
      off[((size_t)(b*81 + o))*S + sa] = accA[j];
      off[((size_t)(b*81 + o))*S + sb] = accB[j];
    }
  }
}

// ---------------- K10 (NEW): deformable conv, fused gather + micro-tiled GEMM ----
// Grid: 1024 = b(2) * s-tile(512 of 64). Block 256. All 27 taps per block, no atomics.
// Per tap: coords in registers (lane = s, gathers near-coalesced), samp tile in LDS,
// then 4o x 4s per-thread GEMM with float4 LDS reads.
__global__ __launch_bounds__(256) void k_dcn(const float* __restrict__ a2,
    const float* __restrict__ off, const float* __restrict__ off_b,
    const float* __restrict__ wt, float* __restrict__ out) {
  __shared__ float wsh[64*68];            // [c][o], 17.4 KB
  __shared__ float smp[64*68];            // [c][s], 17.4 KB
  int bi = blockIdx.x;
  int b = bi >> 9, tile = bi & 511;
  int s0 = tile << 6;
  int tid = threadIdx.x;
  int lane = tid & 63, wv = tid >> 6;
  int s = s0 + lane;
  int z = s >> 10, y = (s >> 5) & 31, x = s & 31;
  int tr = tid >> 4, tc = tid & 15;
  float acc[4][4];
#pragma unroll
  for (int i = 0; i < 4; i++)
#pragma unroll
    for (int j = 0; j < 4; j++) acc[i][j] = 0.f;
  const float* a2b = a2 + ((size_t)b << 21);
  const float* offb = off + (size_t)(b*81)*S;
  for (int k = 0; k < 27; k++) {
    __syncthreads();
    // stage weights [c][o]
    for (int i = tid; i < 4096; i += 256)
      wsh[(i >> 6)*68 + (i & 63)] = wt[(k << 12) + i];
    // coords in registers (redundant across the 4 waves, cheap)
    int kz = k/9, ky = (k/3)%3, kx = k%3;
    float pz = (float)(z + kz - 1) + offb[(size_t)(3*k+0)*S + s] + off_b[3*k+0];
    float py = (float)(y + ky - 1) + offb[(size_t)(3*k+1)*S + s] + off_b[3*k+1];
    float px = (float)(x + kx - 1) + offb[(size_t)(3*k+2)*S + s] + off_b[3*k+2];
    float fz = floorf(pz), fy = floorf(py), fx = floorf(px);
    float wz = pz-fz, wy = py-fy, wx = px-fx;
    int z0 = (int)fz, y0 = (int)fy, x0 = (int)fx;
    int off8[8]; float w8[8];
#pragma unroll
    for (int r = 0; r < 8; r++) {
      int dz = r>>2, dy = (r>>1)&1, dx = r&1;
      int iz = z0+dz, iy = y0+dy, ix = x0+dx;
      bool valid = (iz>=0 && iz<32 && iy>=0 && iy<32 && ix>=0 && ix<32);
      int czi = min(max(iz,0),31), cyi = min(max(iy,0),31), cxi = min(max(ix,0),31);
      off8[r] = czi*1024 + cyi*32 + cxi;
      float cwv = (dz?wz:1.f-wz)*(dy?wy:1.f-wy)*(dx?wx:1.f-wx);
      w8[r] = valid ? cwv : 0.f;
    }
    // sample tile: wave wv covers channels wv*16..wv*16+15, lane = s
#pragma unroll 4
    for (int j = 0; j < 16; j++) {
      int c = (wv << 4) + j;
      const float* base = a2b + ((size_t)c << 15);
      float sv = 0.f;
#pragma unroll
      for (int r = 0; r < 8; r++) sv += w8[r] * base[off8[r]];
      smp[c*68 + lane] = sv;
    }
    __syncthreads();
    // GEMM: 4o x 4s micro-tile
#pragma unroll 8
    for (int c = 0; c < 64; c++) {
      float4 wq = *(const float4*)&wsh[c*68 + (tr<<2)];
      float4 sq = *(const float4*)&smp[c*68 + (tc<<2)];
      acc[0][0] += wq.x*sq.x; acc[0][1] += wq.x*sq.y; acc[0][2] += wq.x*sq.z; acc[0][3] += wq.x*sq.w;
      acc[1][0] += wq.y*sq.x; acc[1][1] += wq.y*sq.y; acc[1][2] += wq.y*sq.z; acc[1][3] += wq.y*sq.w;
      acc[2][0] += wq.z*sq.x; acc[2][1] += wq.z*sq.y; acc[2][2] += wq.z*sq.z; acc[2][3] += wq.z*sq.w;
      acc[3][0] += wq.w*sq.x; acc[3][1] += wq.w*sq.y; acc[3][2] += wq.w*sq.z; acc[3][3] += wq.w*sq.w;
    }
  }
#pragma unroll
  for (int jo = 0; jo < 4; jo++) {
    float4 st; st.x = acc[jo][0]; st.y = acc[jo][1]; st.z = acc[jo][2]; st.w = acc[jo][3];
    *(float4*)&out[((size_t)(b*64 + (tr<<2)+jo))*S + s0 + (tc<<2)] = st;
  }
}

// ---------------- K11: conv1(+dcn_b) -> gate -> proj2 + shortcut ----------
__global__ __launch_bounds__(256) void k_fuse2(const float* __restrict__ dcn,
    const float* __restrict__ dcn_b, const float* __restrict__ c1w,
    const float* __restrict__ c1b, const float* __restrict__ u,
    const float* __restrict__ p2w, const float* __restrict__ p2b,
    const float* __restrict__ x5, float* __restrict__ y2) {
  __shared__ float w1[4096], w2[4096];
  __shared__ float b1[64], b2[64], db[64];
  int gid = blockIdx.x*256 + threadIdx.x;
  for (int i = threadIdx.x; i < 4096; i += 256) { w1[i] = c1w[i]; w2[i] = p2w[i]; }
  if (threadIdx.x < 64) {
    b1[threadIdx.x]=c1b[threadIdx.x]; b2[threadIdx.x]=p2b[threadIdx.x];
    db[threadIdx.x]=dcn_b[threadIdx.x];
  }
  __syncthreads();
  int b = gid >> 15, n = gid & (S-1);
  const float* dbp = dcn + (size_t)b*64*S + n;
  float dv[64];
#pragma unroll
  for (int c = 0; c < 64; c++) dv[c] = dbp[(size_t)c*S] + db[c];
  const float* ub = u + (size_t)b*64*S + n;
  float m[64];
  for (int o = 0; o < 64; o++) {
    float a = b1[o];
#pragma unroll
    for (int c = 0; c < 64; c++) a += w1[o*64+c]*dv[c];
    m[o] = ub[(size_t)o*S] * a;
  }
  const float* sb = x5 + (size_t)b*64*S + n;
  float* yb = y2 + (size_t)b*64*S + n;
  for (int o = 0; o < 64; o++) {
    float a = b2[o];
#pragma unroll
    for (int c = 0; c < 64; c++) a += w2[o*64+c]*m[c];
    yb[(size_t)o*S] = a + sb[(size_t)o*S];
  }
}

// ---------------- K12: reshape-scramble + LN2 + out proj ----------------
__global__ __launch_bounds__(256) void k_final(const float* __restrict__ y2,
    const float* __restrict__ n2w, const float* __restrict__ n2b,
    const float* __restrict__ ow, const float* __restrict__ ob, float* __restrict__ out) {
  __shared__ float wsh[4096];
  __shared__ float nw[64], nb[64], obs[64];
  int bi = blockIdx.x;
  int b = bi >> 7; int mg = (bi >> 4) & 7; int r0 = (bi & 15)*4;
  for (int i = threadIdx.x; i < 4096; i += 256) wsh[i] = ow[i];
  if (threadIdx.x < 64) {
    nw[threadIdx.x]=n2w[threadIdx.x]; nb[threadIdx.x]=n2b[threadIdx.x];
    obs[threadIdx.x]=ob[threadIdx.x];
  }
  __syncthreads();
  int mi = threadIdx.x & 63, rg = threadIdx.x >> 6;
  int r = r0 + rg;
  int m = mg*64 + mi;
  int n = m*64 + r;
  const float* yb = y2 + ((size_t)(b*64+r))*S + m;
  float v[64];
#pragma unroll
  for (int c = 0; c < 64; c++) v[c] = yb[(size_t)c*512];
  float mean = 0.f;
#pragma unroll
  for (int c = 0; c < 64; c++) mean += v[c];
  mean *= (1.0f/64.0f);
  float var = 0.f;
#pragma unroll
  for (int c = 0; c < 64; c++) { float d = v[c]-mean; var += d*d; }
  var *= (1.0f/64.0f);
  float rs = rsqrtf(var + 1e-5f);
#pragma unroll
  for (int c = 0; c < 64; c++) v[c] = (v[c]-mean)*rs*nw[c] + nb[c];
  float* orow = out + ((size_t)b*S + n)*64;
  for (int o4 = 0; o4 < 16; o4++) {
    float4 a;
    float t0=obs[o4*4+0], t1=obs[o4*4+1], t2=obs[o4*4+2], t3=obs[o4*4+3];
#pragma unroll
    for (int c = 0; c < 64; c++) {
      float lv = v[c];
      t0 += wsh[(o4*4+0)*64+c]*lv; t1 += wsh[(o4*4+1)*64+c]*lv;
      t2 += wsh[(o4*4+2)*64+c]*lv; t3 += wsh[(o4*4+3)*64+c]*lv;
    }
    a.x=t0; a.y=t1; a.z=t2; a.w=t3;
    ((float4*)orow)[o4] = a;
  }
}

extern "C" void kernel_launch(void* const* d_in, const int* in_sizes, int n_in,
                              void* d_out, int out_size, void* d_ws, size_t ws_size,
                              hipStream_t stream) {
  const float* x      = (const float*)d_in[0];
  const float* temp   = (const float*)d_in[1];
  const float* qkv_w  = (const float*)d_in[2];
  const float* norm_w = (const float*)d_in[3];
  const float* norm_b = (const float*)d_in[4];
  const float* p1w    = (const float*)d_in[5];
  const float* p1b    = (const float*)d_in[6];
  const float* c0w    = (const float*)d_in[7];
  const float* c0b    = (const float*)d_in[8];
  const float* cspw   = (const float*)d_in[9];
  const float* cspb   = (const float*)d_in[10];
  const float* offw   = (const float*)d_in[11];
  const float* offb   = (const float*)d_in[12];
  const float* dcnw   = (const float*)d_in[13];
  const float* dcnb   = (const float*)d_in[14];
  const float* c1w    = (const float*)d_in[15];
  const float* c1b    = (const float*)d_in[16];
  const float* p2w    = (const float*)d_in[17];
  const float* p2b    = (const float*)d_in[18];
  const float* n2w    = (const float*)d_in[19];
  const float* n2b    = (const float*)d_in[20];
  const float* outw   = (const float*)d_in[21];
  const float* outb   = (const float*)d_in[22];
  float* out = (float*)d_out;

  float* Wa  = (float*)d_ws;                  // q -> x5
  float* Wb  = Wa + BUFN;                     // k -> u
  float* Wc  = Wb + BUFN;                     // a2 -> y2
  float* OFF = Wc + BUFN;                     // 2*81*32768 floats
  float* SM  = OFF + (size_t)2*81*S;          // inv[256], gram[2048], attn[2048]
  float* SM_inv  = SM;
  float* SM_gram = SM + 256;
  float* SM_attn = SM + 2304;
  float* WT_OFF = SM + 4352;                  // 139968 floats
  float* WT_DCN = WT_OFF + 139968;            // 110592 floats
  float* vbuf = out;                          // d_out doubles as scratch: v -> a1 -> dcn

  hipMemsetAsync(SM, 0, 4352*sizeof(float), stream);
  k_wt     <<<547, 256, 0, stream>>>(offw, dcnw, WT_OFF, WT_DCN);

  k_qkv    <<<512, 256, 0, stream>>>(x, qkv_w, Wa, Wb, vbuf);
  k_rownorm<<<256, 256, 0, stream>>>(Wa, Wb, SM_inv);
  k_gram   <<<256, 256, 0, stream>>>(Wa, Wb, SM_gram);
  k_attnsm <<<1,   128, 0, stream>>>(SM_gram, SM_inv, temp, SM_attn);
  k_xca_ln <<<256, 256, 0, stream>>>(vbuf, SM_attn, norm_w, norm_b, Wa);   // x5 -> Wa
  k_proj1  <<<512, 256, 0, stream>>>(Wa, p1w, p1b, Wb);                    // u -> Wb
  k_conv0  <<<512, 256, 0, stream>>>(Wb, c0w, c0b, vbuf);                  // a1 -> d_out
  k_convsp <<<4096,256, 0, stream>>>(vbuf, cspw, cspb, Wc);                // a2 -> Wc
  k_offconv<<<512, 256, 0, stream>>>(Wc, WT_OFF, OFF);
  k_dcn    <<<1024,256, 0, stream>>>(Wc, OFF, offb, WT_DCN, vbuf);         // dcn -> d_out
  k_fuse2  <<<256, 256, 0, stream>>>(vbuf, dcnb, c1w, c1b, Wb, p2w, p2b, Wa, Wc); // y2 -> Wc
  k_final  <<<256, 256, 0, stream>>>(Wc, n2w, n2b, outw, outb, out);
}

// Round 3
// 1650.017 us; speedup vs baseline: 2.7554x; 1.4598x over previous
//
#include <hip/hip_runtime.h>
#include <hip/hip_bf16.h>

#define S 32768
#define BUFN (2*64*32768)

// ---------------- K0: weight transposes (one-off, tiny) ----------------
__global__ void k_wt(const float* __restrict__ offw, const float* __restrict__ dcnw,
                     float* __restrict__ wt_off, float* __restrict__ wt_dcn) {
  int i = blockIdx.x*256 + threadIdx.x;
  if (i < 139968) {
    int o = i % 81, c = (i/81) & 63, t = i / 5184;
    wt_off[i] = offw[o*1728 + c*27 + t];
  }
  if (i < 110592) {
    int o = i & 63, c = (i >> 6) & 63, k = i >> 12;
    wt_dcn[i] = dcnw[(o*64 + c)*27 + k];
  }
}

// ---------------- K1: qkv ----------------
__global__ __launch_bounds__(256) void k_qkv(const float* __restrict__ x,
    const float* __restrict__ qkv_w, float* __restrict__ q,
    float* __restrict__ k, float* __restrict__ v) {
  __shared__ float wsm[96*64];
  int half = blockIdx.x >> 8;
  int gid  = ((blockIdx.x & 255) << 8) + threadIdx.x;
  int rbase = half * 96;
  for (int i = threadIdx.x; i < 96*64; i += 256) wsm[i] = qkv_w[rbase*64 + i];
  __syncthreads();
  int b = gid >> 15, n = gid & (S-1);
  const float* xr = x + (size_t)gid * 64;
  float xv[64];
#pragma unroll
  for (int i = 0; i < 16; i++) {
    float4 t = ((const float4*)xr)[i];
    xv[4*i]=t.x; xv[4*i+1]=t.y; xv[4*i+2]=t.z; xv[4*i+3]=t.w;
  }
  for (int r = 0; r < 96; r++) {
    float acc = 0.f;
#pragma unroll
    for (int c = 0; c < 64; c++) acc += xv[c] * wsm[r*64+c];
    int row = rbase + r;
    float* dst = (row < 64) ? q : (row < 128 ? k : v);
    int ch = row & 63;
    dst[((size_t)(b*64 + ch))*S + n] = acc;
  }
}

// ---------------- K2: per-row inv L2 norm of q,k ----------------
__global__ __launch_bounds__(256) void k_rownorm(const float* __restrict__ q,
    const float* __restrict__ k, float* __restrict__ inv) {
  int row = blockIdx.x;
  const float* p = (row < 128) ? (q + (size_t)row*S) : (k + (size_t)(row-128)*S);
  const float4* p4 = (const float4*)p;
  float ss = 0.f;
  for (int i = threadIdx.x; i < S/4; i += 256) {
    float4 t = p4[i];
    ss += t.x*t.x + t.y*t.y + t.z*t.z + t.w*t.w;
  }
  __shared__ float red[256];
  red[threadIdx.x] = ss; __syncthreads();
  for (int st = 128; st > 0; st >>= 1) {
    if (threadIdx.x < st) red[threadIdx.x] += red[threadIdx.x+st];
    __syncthreads();
  }
  if (threadIdx.x == 0) inv[row] = 1.0f / fmaxf(sqrtf(red[0]), 1e-12f);
}

// ---------------- K3: gram ----------------
__global__ __launch_bounds__(256) void k_gram(const float* __restrict__ q,
    const float* __restrict__ k, float* __restrict__ gram) {
  __shared__ float qt[16][65], kt[16][65];
  int bi = blockIdx.x;
  int b = bi >> 7, h = (bi >> 5) & 3, chunk = bi & 31;
  int c = threadIdx.x >> 4, d = threadIdx.x & 15;
  const float* qb = q + ((size_t)(b*64 + h*16))*S;
  const float* kb = k + ((size_t)(b*64 + h*16))*S;
  int lr = threadIdx.x >> 4, lc = (threadIdx.x & 15) * 4;
  float acc = 0.f;
  for (int n0 = chunk*1024; n0 < chunk*1024 + 1024; n0 += 64) {
    float4 tq = *(const float4*)(qb + (size_t)lr*S + n0 + lc);
    float4 tk = *(const float4*)(kb + (size_t)lr*S + n0 + lc);
    __syncthreads();
    qt[lr][lc]=tq.x; qt[lr][lc+1]=tq.y; qt[lr][lc+2]=tq.z; qt[lr][lc+3]=tq.w;
    kt[lr][lc]=tk.x; kt[lr][lc+1]=tk.y; kt[lr][lc+2]=tk.z; kt[lr][lc+3]=tk.w;
    __syncthreads();
#pragma unroll
    for (int nn = 0; nn < 64; nn++) acc += qt[c][nn]*kt[d][nn];
  }
  atomicAdd(&gram[((b*4+h)*16+c)*16 + d], acc);
}

// ---------------- K4: softmax ----------------
__global__ void k_attnsm(const float* __restrict__ gram, const float* __restrict__ inv,
    const float* __restrict__ temp, float* __restrict__ attn) {
  int t = threadIdx.x; if (t >= 128) return;
  int b = t >> 6, h = (t >> 4) & 3, c = t & 15;
  float iq = inv[b*64 + h*16 + c];
  float tp = temp[h];
  float l[16], m = -1e30f;
#pragma unroll
  for (int d = 0; d < 16; d++) {
    float vv = gram[((b*4+h)*16+c)*16 + d] * iq * inv[128 + b*64 + h*16 + d] * tp;
    l[d] = vv; m = fmaxf(m, vv);
  }
  float s = 0.f;
#pragma unroll
  for (int d = 0; d < 16; d++) { l[d] = expf(l[d]-m); s += l[d]; }
  float is = 1.0f / s;
#pragma unroll
  for (int d = 0; d < 16; d++) attn[((b*4+h)*16+c)*16 + d] = l[d]*is;
}

// ---------------- K5: x_ca = attn@v, layernorm, store x5 ----------------
__global__ __launch_bounds__(256) void k_xca_ln(const float* __restrict__ v,
    const float* __restrict__ attn, const float* __restrict__ nw,
    const float* __restrict__ nb, float* __restrict__ x5) {
  __shared__ float at[1024];
  __shared__ float wsh[64], bsh[64];
  int gid = blockIdx.x*256 + threadIdx.x;
  int b = gid >> 15, n = gid & (S-1);
  for (int i = threadIdx.x; i < 1024; i += 256) at[i] = attn[b*1024 + i];
  if (threadIdx.x < 64) { wsh[threadIdx.x]=nw[threadIdx.x]; bsh[threadIdx.x]=nb[threadIdx.x]; }
  __syncthreads();
  const float* vb = v + (size_t)b*64*S + n;
  float vv[64];
#pragma unroll
  for (int ch = 0; ch < 64; ch++) vv[ch] = vb[(size_t)ch*S];
  float xc[64];
#pragma unroll
  for (int h = 0; h < 4; h++)
#pragma unroll
    for (int cc = 0; cc < 16; cc++) {
      float a = 0.f;
#pragma unroll
      for (int d = 0; d < 16; d++) a += at[(h*16+cc)*16 + d] * vv[h*16+d];
      xc[h*16+cc] = a;
    }
  float mean = 0.f;
#pragma unroll
  for (int ch = 0; ch < 64; ch++) mean += xc[ch];
  mean *= (1.0f/64.0f);
  float var = 0.f;
#pragma unroll
  for (int ch = 0; ch < 64; ch++) { float d = xc[ch]-mean; var += d*d; }
  var *= (1.0f/64.0f);
  float rs = rsqrtf(var + 1e-5f);
  float* xb = x5 + (size_t)b*64*S + n;
#pragma unroll
  for (int ch = 0; ch < 64; ch++)
    xb[(size_t)ch*S] = (xc[ch]-mean)*rs*wsh[ch] + bsh[ch];
}

// ---------------- K6: proj1 + GELU ----------------
__global__ __launch_bounds__(256) void k_proj1(const float* __restrict__ x5,
    const float* __restrict__ w, const float* __restrict__ bias, float* __restrict__ u) {
  __shared__ float wsm[32*64];
  __shared__ float bsm[32];
  int half = blockIdx.x >> 8;
  int gid = ((blockIdx.x & 255) << 8) + threadIdx.x;
  int o0 = half*32;
  for (int i = threadIdx.x; i < 32*64; i += 256) wsm[i] = w[o0*64 + i];
  if (threadIdx.x < 32) bsm[threadIdx.x] = bias[o0 + threadIdx.x];
  __syncthreads();
  int b = gid >> 15, n = gid & (S-1);
  const float* xb = x5 + (size_t)b*64*S + n;
  float xv[64];
#pragma unroll
  for (int ch = 0; ch < 64; ch++) xv[ch] = xb[(size_t)ch*S];
  float* ub = u + (size_t)b*64*S + n;
  for (int oo = 0; oo < 32; oo++) {
    float acc = bsm[oo];
#pragma unroll
    for (int c = 0; c < 64; c++) acc += wsm[oo*64+c]*xv[c];
    float g = 0.5f*acc*(1.0f + erff(acc*0.70710678118654752f));
    ub[(size_t)(o0+oo)*S] = g;
  }
}

// ---------------- K7 v3: depthwise 5^3 pad 2, register-row ILP ----------------
// Grid 4096 = b(2)*c(64)*z(32), 128 threads. Thread = (y, 8-consec-x).
// LDS tile: 5 planes, x-padded rows (stride 36 floats = 144B, 16B-aligned).
__global__ __launch_bounds__(128) void k_conv0(const float* __restrict__ in,
    const float* __restrict__ w, const float* __restrict__ bias, float* __restrict__ out) {
  __shared__ float tile[5*32*36];     // 23040 B
  __shared__ float wsh[125];
  int bi = blockIdx.x;
  int z = bi & 31, c = (bi >> 5) & 63, b = bi >> 11;
  const float* ib = in + ((size_t)(b*64+c) << 15);
  for (int i = threadIdx.x; i < 5*32*36/4; i += 128)
    ((float4*)tile)[i] = make_float4(0.f,0.f,0.f,0.f);
  if (threadIdx.x < 125) wsh[threadIdx.x] = w[c*125 + threadIdx.x];
  __syncthreads();
  for (int i = threadIdx.x; i < 5*1024; i += 128) {
    int dz = i >> 10, r = i & 1023;
    int zg = z + dz - 2;
    if (zg >= 0 && zg < 32)
      tile[(dz*32 + (r >> 5))*36 + (r & 31) + 2] = ib[zg*1024 + r];
  }
  __syncthreads();
  int y = threadIdx.x >> 2, x0 = (threadIdx.x & 3) << 3;
  float bv = bias[c];
  float acc[8];
#pragma unroll
  for (int j = 0; j < 8; j++) acc[j] = bv;
  for (int dz = 0; dz < 5; dz++) {
#pragma unroll
    for (int dy = 0; dy < 5; dy++) {
      int yy = y + dy - 2;
      if (yy < 0 || yy >= 32) continue;
      const float* wp = &wsh[(dz*5+dy)*5];
      float wreg[5];
#pragma unroll
      for (int dx = 0; dx < 5; dx++) wreg[dx] = wp[dx];
      const float* rp = &tile[(dz*32+yy)*36 + x0];
      float4 r0 = ((const float4*)rp)[0];
      float4 r1 = ((const float4*)rp)[1];
      float4 r2 = ((const float4*)rp)[2];
      float row[12] = {r0.x,r0.y,r0.z,r0.w, r1.x,r1.y,r1.z,r1.w, r2.x,r2.y,r2.z,r2.w};
#pragma unroll
      for (int dx = 0; dx < 5; dx++)
#pragma unroll
        for (int j = 0; j < 8; j++)
          acc[j] += wreg[dx] * row[dx+j];
    }
  }
  float* ob = out + ((size_t)(b*64+c) << 15) + z*1024 + y*32 + x0;
  float4 s0; s0.x=acc[0]; s0.y=acc[1]; s0.z=acc[2]; s0.w=acc[3];
  float4 s1; s1.x=acc[4]; s1.y=acc[5]; s1.z=acc[6]; s1.w=acc[7];
  ((float4*)ob)[0] = s0; ((float4*)ob)[1] = s1;
}

// ---------------- K8 v3: depthwise 7^3 dil 3 pad 9, register-row ILP ----------------
// Grid 4096 = b(2)*c(64)*z(32), 128 threads. Thread = (y, 8-consec-x).
// LDS tile: 7 planes, x-padded rows (stride 52 floats = 208B, 16B-aligned).
__global__ __launch_bounds__(128) void k_convsp(const float* __restrict__ in,
    const float* __restrict__ w, const float* __restrict__ bias, float* __restrict__ out) {
  __shared__ float tile[7*32*52];     // 46592 B
  __shared__ float wsh[344];
  int bi = blockIdx.x;
  int z = bi & 31, c = (bi >> 5) & 63, b = bi >> 11;
  const float* ib = in + ((size_t)(b*64+c) << 15);
  for (int i = threadIdx.x; i < 7*32*52/4; i += 128)
    ((float4*)tile)[i] = make_float4(0.f,0.f,0.f,0.f);
  for (int i = threadIdx.x; i < 343; i += 128) wsh[i] = w[c*343 + i];
  __syncthreads();
  for (int i = threadIdx.x; i < 7*1024; i += 128) {
    int t = i >> 10, r = i & 1023;
    int zg = z + 3*t - 9;
    if (zg >= 0 && zg < 32)
      tile[(t*32 + (r >> 5))*52 + (r & 31) + 9] = ib[zg*1024 + r];
  }
  __syncthreads();
  int y = threadIdx.x >> 2, x0 = (threadIdx.x & 3) << 3;
  float bv = bias[c];
  float acc[8];
#pragma unroll
  for (int j = 0; j < 8; j++) acc[j] = bv;
  for (int t = 0; t < 7; t++) {
#pragma unroll
    for (int dy = 0; dy < 7; dy++) {
      int yy = y + 3*dy - 9;
      if (yy < 0 || yy >= 32) continue;
      const float* wp = &wsh[(t*7+dy)*7];
      float wreg[7];
#pragma unroll
      for (int dx = 0; dx < 7; dx++) wreg[dx] = wp[dx];
      const float* rp = &tile[(t*32+yy)*52 + x0];
      float4 r0 = ((const float4*)rp)[0];
      float4 r1 = ((const float4*)rp)[1];
      float4 r2 = ((const float4*)rp)[2];
      float4 r3 = ((const float4*)rp)[3];
      float4 r4 = ((const float4*)rp)[4];
      float4 r5 = ((const float4*)rp)[5];
      float4 r6 = ((const float4*)rp)[6];
      float row[28] = {r0.x,r0.y,r0.z,r0.w, r1.x,r1.y,r1.z,r1.w,
                       r2.x,r2.y,r2.z,r2.w, r3.x,r3.y,r3.z,r3.w,
                       r4.x,r4.y,r4.z,r4.w, r5.x,r5.y,r5.z,r5.w,
                       r6.x,r6.y,r6.z,r6.w};
#pragma unroll
      for (int dx = 0; dx < 7; dx++)
#pragma unroll
        for (int j = 0; j < 8; j++)
          acc[j] += wreg[dx] * row[3*dx+j];
    }
  }
  float* ob = out + ((size_t)(b*64+c) << 15) + z*1024 + y*32 + x0;
  float4 s0; s0.x=acc[0]; s0.y=acc[1]; s0.z=acc[2]; s0.w=acc[3];
  float4 s1; s1.x=acc[4]; s1.y=acc[5]; s1.z=acc[6]; s1.w=acc[7];
  ((float4*)ob)[0] = s0; ((float4*)ob)[1] = s1;
}

// ---------------- K9: offset conv as register-blocked GEMM ----------------
__global__ __launch_bounds__(256) void k_offconv(const float* __restrict__ a2,
    const float* __restrict__ wt, float* __restrict__ off) {
  __shared__ float wsh[64*96];
  int bi = blockIdx.x;
  int b = bi >> 8, tile = bi & 255;
  int s0 = tile << 7;
  int tid = threadIdx.x;
  int og = tid >> 6, sp = tid & 63;
  int sa = s0 + sp, sb = sa + 64;
  int z  = s0 >> 10;
  int ya = (sa >> 5) & 31, xa = sa & 31;
  int yb = (sb >> 5) & 31, xb = sb & 31;
  float accA[21], accB[21];
#pragma unroll
  for (int j = 0; j < 21; j++) { accA[j] = 0.f; accB[j] = 0.f; }
  const float* a2b = a2 + ((size_t)b << 21);
  for (int t = 0; t < 27; t++) {
    int kz = t/9, ky = (t/3)%3, kx = t%3;
    __syncthreads();
    for (int i = tid; i < 6144; i += 256) {
      int c = i/96, r = i%96, qt = r/24, j = r%24;
      int o = qt*21 + j;
      wsh[i] = (j < 21 && o < 81) ? wt[(t*64 + c)*81 + o] : 0.f;
    }
    __syncthreads();
    int zz = z + kz - 1;
    int yya = ya + ky - 1, xxa = xa + kx - 1;
    int yyb = yb + ky - 1, xxb = xb + kx - 1;
    bool va = (zz>=0 && zz<32 && yya>=0 && yya<32 && xxa>=0 && xxa<32);
    bool vb = (zz>=0 && zz<32 && yyb>=0 && yyb<32 && xxb>=0 && xxb<32);
    int ia = zz*1024 + yya*32 + xxa;
    int ib = zz*1024 + yyb*32 + xxb;
#pragma unroll 8
    for (int c = 0; c < 64; c++) {
      const float* base = a2b + ((size_t)c << 15);
      float vA = va ? base[ia] : 0.f;
      float vB = vb ? base[ib] : 0.f;
      const float* wq = &wsh[c*96 + og*24];
      float4 w0 = ((const float4*)wq)[0];
      float4 w1 = ((const float4*)wq)[1];
      float4 w2 = ((const float4*)wq)[2];
      float4 w3 = ((const float4*)wq)[3];
      float4 w4 = ((const float4*)wq)[4];
      float4 w5 = ((const float4*)wq)[5];
      float wr[24] = {w0.x,w0.y,w0.z,w0.w, w1.x,w1.y,w1.z,w1.w,
                      w2.x,w2.y,w2.z,w2.w, w3.x,w3.y,w3.z,w3.w,
                      w4.x,w4.y,w4.z,w4.w, w5.x,w5.y,w5.z,w5.w};
#pragma unroll
      for (int j = 0; j < 21; j++) {
        accA[j] += wr[j]*vA;
        accB[j] += wr[j]*vB;
      }
    }
  }
#pragma unroll
  for (int j = 0; j < 21; j++) {
    int o = og*21 + j;
    if (o < 81) {
      off[((size_t)(b*81 + o))*S + sa] = accA[j];
      off[((size_t)(b*81 + o))*S + sb] = accB[j];
    }
  }
}

// ---------------- K10: deformable conv, fused gather + micro-tiled GEMM ----
__global__ __launch_bounds__(256) void k_dcn(const float* __restrict__ a2,
    const float* __restrict__ off, const float* __restrict__ off_b,
    const float* __restrict__ wt, float* __restrict__ out) {
  __shared__ float wsh[64*68];
  __shared__ float smp[64*68];
  int bi = blockIdx.x;
  int b = bi >> 9, tile = bi & 511;
  int s0 = tile << 6;
  int tid = threadIdx.x;
  int lane = tid & 63, wv = tid >> 6;
  int s = s0 + lane;
  int z = s >> 10, y = (s >> 5) & 31, x = s & 31;
  int tr = tid >> 4, tc = tid & 15;
  float acc[4][4];
#pragma unroll
  for (int i = 0; i < 4; i++)
#pragma unroll
    for (int j = 0; j < 4; j++) acc[i][j] = 0.f;
  const float* a2b = a2 + ((size_t)b << 21);
  const float* offb = off + (size_t)(b*81)*S;
  for (int k = 0; k < 27; k++) {
    __syncthreads();
    for (int i = tid; i < 4096; i += 256)
      wsh[(i >> 6)*68 + (i & 63)] = wt[(k << 12) + i];
    int kz = k/9, ky = (k/3)%3, kx = k%3;
    float pz = (float)(z + kz - 1) + offb[(size_t)(3*k+0)*S + s] + off_b[3*k+0];
    float py = (float)(y + ky - 1) + offb[(size_t)(3*k+1)*S + s] + off_b[3*k+1];
    float px = (float)(x + kx - 1) + offb[(size_t)(3*k+2)*S + s] + off_b[3*k+2];
    float fz = floorf(pz), fy = floorf(py), fx = floorf(px);
    float wz = pz-fz, wy = py-fy, wx = px-fx;
    int z0 = (int)fz, y0 = (int)fy, x0 = (int)fx;
    int off8[8]; float w8[8];
#pragma unroll
    for (int r = 0; r < 8; r++) {
      int dz = r>>2, dy = (r>>1)&1, dx = r&1;
      int iz = z0+dz, iy = y0+dy, ix = x0+dx;
      bool valid = (iz>=0 && iz<32 && iy>=0 && iy<32 && ix>=0 && ix<32);
      int czi = min(max(iz,0),31), cyi = min(max(iy,0),31), cxi = min(max(ix,0),31);
      off8[r] = czi*1024 + cyi*32 + cxi;
      float cwv = (dz?wz:1.f-wz)*(dy?wy:1.f-wy)*(dx?wx:1.f-wx);
      w8[r] = valid ? cwv : 0.f;
    }
#pragma unroll 4
    for (int j = 0; j < 16; j++) {
      int c = (wv << 4) + j;
      const float* base = a2b + ((size_t)c << 15);
      float sv = 0.f;
#pragma unroll
      for (int r = 0; r < 8; r++) sv += w8[r] * base[off8[r]];
      smp[c*68 + lane] = sv;
    }
    __syncthreads();
#pragma unroll 8
    for (int c = 0; c < 64; c++) {
      float4 wq = *(const float4*)&wsh[c*68 + (tr<<2)];
      float4 sq = *(const float4*)&smp[c*68 + (tc<<2)];
      acc[0][0] += wq.x*sq.x; acc[0][1] += wq.x*sq.y; acc[0][2] += wq.x*sq.z; acc[0][3] += wq.x*sq.w;
      acc[1][0] += wq.y*sq.x; acc[1][1] += wq.y*sq.y; acc[1][2] += wq.y*sq.z; acc[1][3] += wq.y*sq.w;
      acc[2][0] += wq.z*sq.x; acc[2][1] += wq.z*sq.y; acc[2][2] += wq.z*sq.z; acc[2][3] += wq.z*sq.w;
      acc[3][0] += wq.w*sq.x; acc[3][1] += wq.w*sq.y; acc[3][2] += wq.w*sq.z; acc[3][3] += wq.w*sq.w;
    }
  }
#pragma unroll
  for (int jo = 0; jo < 4; jo++) {
    float4 st; st.x = acc[jo][0]; st.y = acc[jo][1]; st.z = acc[jo][2]; st.w = acc[jo][3];
    *(float4*)&out[((size_t)(b*64 + (tr<<2)+jo))*S + s0 + (tc<<2)] = st;
  }
}

// ---------------- K11: conv1(+dcn_b) -> gate -> proj2 + shortcut ----------
__global__ __launch_bounds__(256) void k_fuse2(const float* __restrict__ dcn,
    const float* __restrict__ dcn_b, const float* __restrict__ c1w,
    const float* __restrict__ c1b, const float* __restrict__ u,
    const float* __restrict__ p2w, const float* __restrict__ p2b,
    const float* __restrict__ x5, float* __restrict__ y2) {
  __shared__ float w1[4096], w2[4096];
  __shared__ float b1[64], b2[64], db[64];
  int gid = blockIdx.x*256 + threadIdx.x;
  for (int i = threadIdx.x; i < 4096; i += 256) { w1[i] = c1w[i]; w2[i] = p2w[i]; }
  if (threadIdx.x < 64) {
    b1[threadIdx.x]=c1b[threadIdx.x]; b2[threadIdx.x]=p2b[threadIdx.x];
    db[threadIdx.x]=dcn_b[threadIdx.x];
  }
  __syncthreads();
  int b = gid >> 15, n = gid & (S-1);
  const float* dbp = dcn + (size_t)b*64*S + n;
  float dv[64];
#pragma unroll
  for (int c = 0; c < 64; c++) dv[c] = dbp[(size_t)c*S] + db[c];
  const float* ub = u + (size_t)b*64*S + n;
  float m[64];
  for (int o = 0; o < 64; o++) {
    float a = b1[o];
#pragma unroll
    for (int c = 0; c < 64; c++) a += w1[o*64+c]*dv[c];
    m[o] = ub[(size_t)o*S] * a;
  }
  const float* sb = x5 + (size_t)b*64*S + n;
  float* yb = y2 + (size_t)b*64*S + n;
  for (int o = 0; o < 64; o++) {
    float a = b2[o];
#pragma unroll
    for (int c = 0; c < 64; c++) a += w2[o*64+c]*m[c];
    yb[(size_t)o*S] = a + sb[(size_t)o*S];
  }
}

// ---------------- K12: reshape-scramble + LN2 + out proj ----------------
__global__ __launch_bounds__(256) void k_final(const float* __restrict__ y2,
    const float* __restrict__ n2w, const float* __restrict__ n2b,
    const float* __restrict__ ow, const float* __restrict__ ob, float* __restrict__ out) {
  __shared__ float wsh[4096];
  __shared__ float nw[64], nb[64], obs[64];
  int bi = blockIdx.x;
  int b = bi >> 7; int mg = (bi >> 4) & 7; int r0 = (bi & 15)*4;
  for (int i = threadIdx.x; i < 4096; i += 256) wsh[i] = ow[i];
  if (threadIdx.x < 64) {
    nw[threadIdx.x]=n2w[threadIdx.x]; nb[threadIdx.x]=n2b[threadIdx.x];
    obs[threadIdx.x]=ob[threadIdx.x];
  }
  __syncthreads();
  int mi = threadIdx.x & 63, rg = threadIdx.x >> 6;
  int r = r0 + rg;
  int m = mg*64 + mi;
  int n = m*64 + r;
  const float* yb = y2 + ((size_t)(b*64+r))*S + m;
  float v[64];
#pragma unroll
  for (int c = 0; c < 64; c++) v[c] = yb[(size_t)c*512];
  float mean = 0.f;
#pragma unroll
  for (int c = 0; c < 64; c++) mean += v[c];
  mean *= (1.0f/64.0f);
  float var = 0.f;
#pragma unroll
  for (int c = 0; c < 64; c++) { float d = v[c]-mean; var += d*d; }
  var *= (1.0f/64.0f);
  float rs = rsqrtf(var + 1e-5f);
#pragma unroll
  for (int c = 0; c < 64; c++) v[c] = (v[c]-mean)*rs*nw[c] + nb[c];
  float* orow = out + ((size_t)b*S + n)*64;
  for (int o4 = 0; o4 < 16; o4++) {
    float4 a;
    float t0=obs[o4*4+0], t1=obs[o4*4+1], t2=obs[o4*4+2], t3=obs[o4*4+3];
#pragma unroll
    for (int c = 0; c < 64; c++) {
      float lv = v[c];
      t0 += wsh[(o4*4+0)*64+c]*lv; t1 += wsh[(o4*4+1)*64+c]*lv;
      t2 += wsh[(o4*4+2)*64+c]*lv; t3 += wsh[(o4*4+3)*64+c]*lv;
    }
    a.x=t0; a.y=t1; a.z=t2; a.w=t3;
    ((float4*)orow)[o4] = a;
  }
}

extern "C" void kernel_launch(void* const* d_in, const int* in_sizes, int n_in,
                              void* d_out, int out_size, void* d_ws, size_t ws_size,
                              hipStream_t stream) {
  const float* x      = (const float*)d_in[0];
  const float* temp   = (const float*)d_in[1];
  const float* qkv_w  = (const float*)d_in[2];
  const float* norm_w = (const float*)d_in[3];
  const float* norm_b = (const float*)d_in[4];
  const float* p1w    = (const float*)d_in[5];
  const float* p1b    = (const float*)d_in[6];
  const float* c0w    = (const float*)d_in[7];
  const float* c0b    = (const float*)d_in[8];
  const float* cspw   = (const float*)d_in[9];
  const float* cspb   = (const float*)d_in[10];
  const float* offw   = (const float*)d_in[11];
  const float* offb   = (const float*)d_in[12];
  const float* dcnw   = (const float*)d_in[13];
  const float* dcnb   = (const float*)d_in[14];
  const float* c1w    = (const float*)d_in[15];
  const float* c1b    = (const float*)d_in[16];
  const float* p2w    = (const float*)d_in[17];
  const float* p2b    = (const float*)d_in[18];
  const float* n2w    = (const float*)d_in[19];
  const float* n2b    = (const float*)d_in[20];
  const float* outw   = (const float*)d_in[21];
  const float* outb   = (const float*)d_in[22];
  float* out = (float*)d_out;

  float* Wa  = (float*)d_ws;                  // q -> x5
  float* Wb  = Wa + BUFN;                     // k -> u
  float* Wc  = Wb + BUFN;                     // a2 -> y2
  float* OFF = Wc + BUFN;
  float* SM  = OFF + (size_t)2*81*S;
  float* SM_inv  = SM;
  float* SM_gram = SM + 256;
  float* SM_attn = SM + 2304;
  float* WT_OFF = SM + 4352;
  float* WT_DCN = WT_OFF + 139968;
  float* vbuf = out;                          // d_out doubles as scratch: v -> a1 -> dcn

  hipMemsetAsync(SM, 0, 4352*sizeof(float), stream);
  k_wt     <<<547, 256, 0, stream>>>(offw, dcnw, WT_OFF, WT_DCN);

  k_qkv    <<<512, 256, 0, stream>>>(x, qkv_w, Wa, Wb, vbuf);
  k_rownorm<<<256, 256, 0, stream>>>(Wa, Wb, SM_inv);
  k_gram   <<<256, 256, 0, stream>>>(Wa, Wb, SM_gram);
  k_attnsm <<<1,   128, 0, stream>>>(SM_gram, SM_inv, temp, SM_attn);
  k_xca_ln <<<256, 256, 0, stream>>>(vbuf, SM_attn, norm_w, norm_b, Wa);   // x5 -> Wa
  k_proj1  <<<512, 256, 0, stream>>>(Wa, p1w, p1b, Wb);                    // u -> Wb
  k_conv0  <<<4096,128, 0, stream>>>(Wb, c0w, c0b, vbuf);                  // a1 -> d_out
  k_convsp <<<4096,128, 0, stream>>>(vbuf, cspw, cspb, Wc);                // a2 -> Wc
  k_offconv<<<512, 256, 0, stream>>>(Wc, WT_OFF, OFF);
  k_dcn    <<<1024,256, 0, stream>>>(Wc, OFF, offb, WT_DCN, vbuf);         // dcn -> d_out
  k_fuse2  <<<256, 256, 0, stream>>>(vbuf, dcnb, c1w, c1b, Wb, p2w, p2b, Wa, Wc); // y2 -> Wc
  k_final  <<<256, 256, 0, stream>>>(Wc, n2w, n2b, outw, outb, out);
}

// Round 4
// 1141.135 us; speedup vs baseline: 3.9841x; 1.4459x over previous
//
#include <hip/hip_runtime.h>
#include <hip/hip_bf16.h>

#define S 32768
#define BUFN (2*64*32768)

typedef __bf16 v8bf __attribute__((ext_vector_type(8)));
typedef float v4f __attribute__((ext_vector_type(4)));

__device__ __forceinline__ ushort f2b(float f) {
  union { float f; unsigned u; } v; v.f = f;
  unsigned r = (v.u + 0x7fffu + ((v.u >> 16) & 1u)) >> 16;
  return (ushort)r;
}
__device__ __forceinline__ float b2f(ushort h) {
  union { unsigned u; float f; } v; v.u = ((unsigned)h) << 16;
  return v.f;
}

// ---------------- K0: weight transpose + bf16 (one-off, tiny) ----------------
// wt_off16[t][o<96][c] (o>=81 zero); wt_dcn16[k][o][c]
__global__ void k_wt(const float* __restrict__ offw, const float* __restrict__ dcnw,
                     ushort* __restrict__ wt_off16, ushort* __restrict__ wt_dcn16) {
  int i = blockIdx.x*256 + threadIdx.x;
  if (i < 27*96*64) {
    int c = i & 63, o = (i >> 6) % 96, t = i / 6144;
    wt_off16[i] = (o < 81) ? f2b(offw[o*1728 + c*27 + t]) : (ushort)0;
  }
  if (i < 27*64*64) {
    int c = i & 63, o = (i >> 6) & 63, k = i >> 12;
    wt_dcn16[i] = f2b(dcnw[(o*64 + c)*27 + k]);
  }
}

// ---------------- K1: qkv ----------------
__global__ __launch_bounds__(256) void k_qkv(const float* __restrict__ x,
    const float* __restrict__ qkv_w, float* __restrict__ q,
    float* __restrict__ k, float* __restrict__ v) {
  __shared__ float wsm[96*64];
  int half = blockIdx.x >> 8;
  int gid  = ((blockIdx.x & 255) << 8) + threadIdx.x;
  int rbase = half * 96;
  for (int i = threadIdx.x; i < 96*64; i += 256) wsm[i] = qkv_w[rbase*64 + i];
  __syncthreads();
  int b = gid >> 15, n = gid & (S-1);
  const float* xr = x + (size_t)gid * 64;
  float xv[64];
#pragma unroll
  for (int i = 0; i < 16; i++) {
    float4 t = ((const float4*)xr)[i];
    xv[4*i]=t.x; xv[4*i+1]=t.y; xv[4*i+2]=t.z; xv[4*i+3]=t.w;
  }
  for (int r = 0; r < 96; r++) {
    float acc = 0.f;
#pragma unroll
    for (int c = 0; c < 64; c++) acc += xv[c] * wsm[r*64+c];
    int row = rbase + r;
    float* dst = (row < 64) ? q : (row < 128 ? k : v);
    int ch = row & 63;
    dst[((size_t)(b*64 + ch))*S + n] = acc;
  }
}

// ---------------- K2: per-row inv L2 norm of q,k ----------------
__global__ __launch_bounds__(256) void k_rownorm(const float* __restrict__ q,
    const float* __restrict__ k, float* __restrict__ inv) {
  int row = blockIdx.x;
  const float* p = (row < 128) ? (q + (size_t)row*S) : (k + (size_t)(row-128)*S);
  const float4* p4 = (const float4*)p;
  float ss = 0.f;
  for (int i = threadIdx.x; i < S/4; i += 256) {
    float4 t = p4[i];
    ss += t.x*t.x + t.y*t.y + t.z*t.z + t.w*t.w;
  }
  __shared__ float red[256];
  red[threadIdx.x] = ss; __syncthreads();
  for (int st = 128; st > 0; st >>= 1) {
    if (threadIdx.x < st) red[threadIdx.x] += red[threadIdx.x+st];
    __syncthreads();
  }
  if (threadIdx.x == 0) inv[row] = 1.0f / fmaxf(sqrtf(red[0]), 1e-12f);
}

// ---------------- K3: gram ----------------
__global__ __launch_bounds__(256) void k_gram(const float* __restrict__ q,
    const float* __restrict__ k, float* __restrict__ gram) {
  __shared__ float qt[16][65], kt[16][65];
  int bi = blockIdx.x;
  int b = bi >> 7, h = (bi >> 5) & 3, chunk = bi & 31;
  int c = threadIdx.x >> 4, d = threadIdx.x & 15;
  const float* qb = q + ((size_t)(b*64 + h*16))*S;
  const float* kb = k + ((size_t)(b*64 + h*16))*S;
  int lr = threadIdx.x >> 4, lc = (threadIdx.x & 15) * 4;
  float acc = 0.f;
  for (int n0 = chunk*1024; n0 < chunk*1024 + 1024; n0 += 64) {
    float4 tq = *(const float4*)(qb + (size_t)lr*S + n0 + lc);
    float4 tk = *(const float4*)(kb + (size_t)lr*S + n0 + lc);
    __syncthreads();
    qt[lr][lc]=tq.x; qt[lr][lc+1]=tq.y; qt[lr][lc+2]=tq.z; qt[lr][lc+3]=tq.w;
    kt[lr][lc]=tk.x; kt[lr][lc+1]=tk.y; kt[lr][lc+2]=tk.z; kt[lr][lc+3]=tk.w;
    __syncthreads();
#pragma unroll
    for (int nn = 0; nn < 64; nn++) acc += qt[c][nn]*kt[d][nn];
  }
  atomicAdd(&gram[((b*4+h)*16+c)*16 + d], acc);
}

// ---------------- K4: softmax ----------------
__global__ void k_attnsm(const float* __restrict__ gram, const float* __restrict__ inv,
    const float* __restrict__ temp, float* __restrict__ attn) {
  int t = threadIdx.x; if (t >= 128) return;
  int b = t >> 6, h = (t >> 4) & 3, c = t & 15;
  float iq = inv[b*64 + h*16 + c];
  float tp = temp[h];
  float l[16], m = -1e30f;
#pragma unroll
  for (int d = 0; d < 16; d++) {
    float vv = gram[((b*4+h)*16+c)*16 + d] * iq * inv[128 + b*64 + h*16 + d] * tp;
    l[d] = vv; m = fmaxf(m, vv);
  }
  float s = 0.f;
#pragma unroll
  for (int d = 0; d < 16; d++) { l[d] = expf(l[d]-m); s += l[d]; }
  float is = 1.0f / s;
#pragma unroll
  for (int d = 0; d < 16; d++) attn[((b*4+h)*16+c)*16 + d] = l[d]*is;
}

// ---------------- K5: x_ca = attn@v, layernorm, store x5 ----------------
__global__ __launch_bounds__(256) void k_xca_ln(const float* __restrict__ v,
    const float* __restrict__ attn, const float* __restrict__ nw,
    const float* __restrict__ nb, float* __restrict__ x5) {
  __shared__ float at[1024];
  __shared__ float wsh[64], bsh[64];
  int gid = blockIdx.x*256 + threadIdx.x;
  int b = gid >> 15, n = gid & (S-1);
  for (int i = threadIdx.x; i < 1024; i += 256) at[i] = attn[b*1024 + i];
  if (threadIdx.x < 64) { wsh[threadIdx.x]=nw[threadIdx.x]; bsh[threadIdx.x]=nb[threadIdx.x]; }
  __syncthreads();
  const float* vb = v + (size_t)b*64*S + n;
  float vv[64];
#pragma unroll
  for (int ch = 0; ch < 64; ch++) vv[ch] = vb[(size_t)ch*S];
  float xc[64];
#pragma unroll
  for (int h = 0; h < 4; h++)
#pragma unroll
    for (int cc = 0; cc < 16; cc++) {
      float a = 0.f;
#pragma unroll
      for (int d = 0; d < 16; d++) a += at[(h*16+cc)*16 + d] * vv[h*16+d];
      xc[h*16+cc] = a;
    }
  float mean = 0.f;
#pragma unroll
  for (int ch = 0; ch < 64; ch++) mean += xc[ch];
  mean *= (1.0f/64.0f);
  float var = 0.f;
#pragma unroll
  for (int ch = 0; ch < 64; ch++) { float d = xc[ch]-mean; var += d*d; }
  var *= (1.0f/64.0f);
  float rs = rsqrtf(var + 1e-5f);
  float* xb = x5 + (size_t)b*64*S + n;
#pragma unroll
  for (int ch = 0; ch < 64; ch++)
    xb[(size_t)ch*S] = (xc[ch]-mean)*rs*wsh[ch] + bsh[ch];
}

// ---------------- K6: proj1 + GELU ----------------
__global__ __launch_bounds__(256) void k_proj1(const float* __restrict__ x5,
    const float* __restrict__ w, const float* __restrict__ bias, float* __restrict__ u) {
  __shared__ float wsm[32*64];
  __shared__ float bsm[32];
  int half = blockIdx.x >> 8;
  int gid = ((blockIdx.x & 255) << 8) + threadIdx.x;
  int o0 = half*32;
  for (int i = threadIdx.x; i < 32*64; i += 256) wsm[i] = w[o0*64 + i];
  if (threadIdx.x < 32) bsm[threadIdx.x] = bias[o0 + threadIdx.x];
  __syncthreads();
  int b = gid >> 15, n = gid & (S-1);
  const float* xb = x5 + (size_t)b*64*S + n;
  float xv[64];
#pragma unroll
  for (int ch = 0; ch < 64; ch++) xv[ch] = xb[(size_t)ch*S];
  float* ub = u + (size_t)b*64*S + n;
  for (int oo = 0; oo < 32; oo++) {
    float acc = bsm[oo];
#pragma unroll
    for (int c = 0; c < 64; c++) acc += wsm[oo*64+c]*xv[c];
    float g = 0.5f*acc*(1.0f + erff(acc*0.70710678118654752f));
    ub[(size_t)(o0+oo)*S] = g;
  }
}

// ---------------- K7: depthwise 5^3 pad 2, register-row ILP ----------------
__global__ __launch_bounds__(128) void k_conv0(const float* __restrict__ in,
    const float* __restrict__ w, const float* __restrict__ bias, float* __restrict__ out) {
  __shared__ float tile[5*32*36];
  __shared__ float wsh[125];
  int bi = blockIdx.x;
  int z = bi & 31, c = (bi >> 5) & 63, b = bi >> 11;
  const float* ib = in + ((size_t)(b*64+c) << 15);
  for (int i = threadIdx.x; i < 5*32*36/4; i += 128)
    ((float4*)tile)[i] = make_float4(0.f,0.f,0.f,0.f);
  if (threadIdx.x < 125) wsh[threadIdx.x] = w[c*125 + threadIdx.x];
  __syncthreads();
  for (int i = threadIdx.x; i < 5*1024; i += 128) {
    int dz = i >> 10, r = i & 1023;
    int zg = z + dz - 2;
    if (zg >= 0 && zg < 32)
      tile[(dz*32 + (r >> 5))*36 + (r & 31) + 2] = ib[zg*1024 + r];
  }
  __syncthreads();
  int y = threadIdx.x >> 2, x0 = (threadIdx.x & 3) << 3;
  float bv = bias[c];
  float acc[8];
#pragma unroll
  for (int j = 0; j < 8; j++) acc[j] = bv;
  for (int dz = 0; dz < 5; dz++) {
#pragma unroll
    for (int dy = 0; dy < 5; dy++) {
      int yy = y + dy - 2;
      if (yy < 0 || yy >= 32) continue;
      const float* wp = &wsh[(dz*5+dy)*5];
      float wreg[5];
#pragma unroll
      for (int dx = 0; dx < 5; dx++) wreg[dx] = wp[dx];
      const float* rp = &tile[(dz*32+yy)*36 + x0];
      float4 r0 = ((const float4*)rp)[0];
      float4 r1 = ((const float4*)rp)[1];
      float4 r2 = ((const float4*)rp)[2];
      float row[12] = {r0.x,r0.y,r0.z,r0.w, r1.x,r1.y,r1.z,r1.w, r2.x,r2.y,r2.z,r2.w};
#pragma unroll
      for (int dx = 0; dx < 5; dx++)
#pragma unroll
        for (int j = 0; j < 8; j++)
          acc[j] += wreg[dx] * row[dx+j];
    }
  }
  float* ob = out + ((size_t)(b*64+c) << 15) + z*1024 + y*32 + x0;
  float4 s0; s0.x=acc[0]; s0.y=acc[1]; s0.z=acc[2]; s0.w=acc[3];
  float4 s1; s1.x=acc[4]; s1.y=acc[5]; s1.z=acc[6]; s1.w=acc[7];
  ((float4*)ob)[0] = s0; ((float4*)ob)[1] = s1;
}

// ---------------- K8: depthwise 7^3 dil 3 pad 9, register-row ILP ----------------
__global__ __launch_bounds__(128) void k_convsp(const float* __restrict__ in,
    const float* __restrict__ w, const float* __restrict__ bias, float* __restrict__ out) {
  __shared__ float tile[7*32*52];
  __shared__ float wsh[344];
  int bi = blockIdx.x;
  int z = bi & 31, c = (bi >> 5) & 63, b = bi >> 11;
  const float* ib = in + ((size_t)(b*64+c) << 15);
  for (int i = threadIdx.x; i < 7*32*52/4; i += 128)
    ((float4*)tile)[i] = make_float4(0.f,0.f,0.f,0.f);
  for (int i = threadIdx.x; i < 343; i += 128) wsh[i] = w[c*343 + i];
  __syncthreads();
  for (int i = threadIdx.x; i < 7*1024; i += 128) {
    int t = i >> 10, r = i & 1023;
    int zg = z + 3*t - 9;
    if (zg >= 0 && zg < 32)
      tile[(t*32 + (r >> 5))*52 + (r & 31) + 9] = ib[zg*1024 + r];
  }
  __syncthreads();
  int y = threadIdx.x >> 2, x0 = (threadIdx.x & 3) << 3;
  float bv = bias[c];
  float acc[8];
#pragma unroll
  for (int j = 0; j < 8; j++) acc[j] = bv;
  for (int t = 0; t < 7; t++) {
#pragma unroll
    for (int dy = 0; dy < 7; dy++) {
      int yy = y + 3*dy - 9;
      if (yy < 0 || yy >= 32) continue;
      const float* wp = &wsh[(t*7+dy)*7];
      float wreg[7];
#pragma unroll
      for (int dx = 0; dx < 7; dx++) wreg[dx] = wp[dx];
      const float* rp = &tile[(t*32+yy)*52 + x0];
      float4 r0 = ((const float4*)rp)[0];
      float4 r1 = ((const float4*)rp)[1];
      float4 r2 = ((const float4*)rp)[2];
      float4 r3 = ((const float4*)rp)[3];
      float4 r4 = ((const float4*)rp)[4];
      float4 r5 = ((const float4*)rp)[5];
      float4 r6 = ((const float4*)rp)[6];
      float row[28] = {r0.x,r0.y,r0.z,r0.w, r1.x,r1.y,r1.z,r1.w,
                       r2.x,r2.y,r2.z,r2.w, r3.x,r3.y,r3.z,r3.w,
                       r4.x,r4.y,r4.z,r4.w, r5.x,r5.y,r5.z,r5.w,
                       r6.x,r6.y,r6.z,r6.w};
#pragma unroll
      for (int dx = 0; dx < 7; dx++)
#pragma unroll
        for (int j = 0; j < 8; j++)
          acc[j] += wreg[dx] * row[3*dx+j];
    }
  }
  float* ob = out + ((size_t)(b*64+c) << 15) + z*1024 + y*32 + x0;
  float4 s0; s0.x=acc[0]; s0.y=acc[1]; s0.z=acc[2]; s0.w=acc[3];
  float4 s1; s1.x=acc[4]; s1.y=acc[5]; s1.z=acc[6]; s1.w=acc[7];
  ((float4*)ob)[0] = s0; ((float4*)ob)[1] = s1;
}

// ---------------- K8b: transpose a2 [C][S] f32 -> a2t [S][C] bf16 ----------------
__global__ __launch_bounds__(256) void k_tr(const float* __restrict__ a2,
                                            ushort* __restrict__ a2t) {
  __shared__ float tile[64*65];
  int bi = blockIdx.x;
  int b = bi >> 9, chunk = bi & 511;
  int s0 = chunk << 6;
  const float* ib = a2 + ((size_t)b << 21) + s0;
#pragma unroll
  for (int i = 0; i < 16; i++) {
    int j = threadIdx.x + (i << 8);
    int c = j >> 6, sl = j & 63;
    tile[c*65 + sl] = ib[((size_t)c << 15) + sl];
  }
  __syncthreads();
  ushort* ob = a2t + ((size_t)b << 21) + ((size_t)s0 << 6);
#pragma unroll
  for (int i = 0; i < 16; i++) {
    int j = threadIdx.x + (i << 8);
    int sl = j >> 6, c = j & 63;
    ob[sl*64 + c] = f2b(tile[c*65 + sl]);
  }
}

// ---------------- K9 v3: offset conv, bf16 MFMA ----------------
// Grid 1024 = b(2)*stile(512 of 64 s). Wave w = s-subtile w; 6 o-tiles (96 o padded).
__global__ __launch_bounds__(256) void k_offconv(const ushort* __restrict__ a2t,
    const ushort* __restrict__ wt16, float* __restrict__ off) {
  __shared__ __align__(16) ushort sB[64*72];
  __shared__ __align__(16) ushort sA[96*72];
  int bi = blockIdx.x;
  int b = bi >> 9, tile = bi & 511;
  int s0 = tile << 6;
  int tid = threadIdx.x;
  int lane = tid & 63, wv = tid >> 6;
  int si = lane & 15, q8 = (lane >> 4) << 3;
  const ushort* a2b = a2t + ((size_t)b << 21);
  v4f acc[6];
#pragma unroll
  for (int i = 0; i < 6; i++) acc[i] = (v4f){0.f,0.f,0.f,0.f};
  for (int t = 0; t < 27; t++) {
    int kz = t/9, ky = (t/3)%3, kx = t%3;
    int delta = (kz-1)*1024 + (ky-1)*32 + (kx-1);
    __syncthreads();
    // stage A: 6144 contiguous ushorts -> sA[o*72+c]
#pragma unroll
    for (int j = 0; j < 3; j++) {
      int chunk = tid + (j << 8);
      int o = chunk >> 3, c0 = (chunk & 7) << 3;
      *(int4*)(&sA[o*72 + c0]) = *(const int4*)(wt16 + t*6144 + chunk*8);
    }
    // stage B: wave wv stages rows 16wv..16wv+15 with zero-fill
#pragma unroll 4
    for (int i = 0; i < 16; i++) {
      int sl = (wv << 4) + i, s = s0 + sl;
      int zz = (s >> 10) + kz - 1, yy = ((s >> 5) & 31) + ky - 1, xx = (s & 31) + kx - 1;
      bool ok = (zz>=0 && zz<32 && yy>=0 && yy<32 && xx>=0 && xx<32);
      ushort val = ok ? a2b[(size_t)(s + delta)*64 + lane] : (ushort)0;
      sB[sl*72 + lane] = val;
    }
    __syncthreads();
    v8bf b0 = *(const v8bf*)(&sB[((wv<<4)+si)*72 + q8]);
    v8bf b1 = *(const v8bf*)(&sB[((wv<<4)+si)*72 + q8 + 32]);
#pragma unroll
    for (int ot = 0; ot < 6; ot++) {
      const ushort* ap = &sA[(ot*16 + si)*72];
      v8bf a0 = *(const v8bf*)(ap + q8);
      v8bf a1 = *(const v8bf*)(ap + q8 + 32);
      acc[ot] = __builtin_amdgcn_mfma_f32_16x16x32_bf16(a0, b0, acc[ot], 0,0,0);
      acc[ot] = __builtin_amdgcn_mfma_f32_16x16x32_bf16(a1, b1, acc[ot], 0,0,0);
    }
  }
  int rq = lane >> 4;
#pragma unroll
  for (int ot = 0; ot < 6; ot++)
#pragma unroll
    for (int r = 0; r < 4; r++) {
      int o = ot*16 + rq*4 + r;
      if (o < 81)
        off[(((size_t)(b*81 + o)) << 15) + s0 + (wv<<4) + si] = acc[ot][r];
    }
}

// ---------------- K10 v3: deformable conv, coalesced gather + bf16 MFMA ----------
// Grid 1024 = b(2)*stile(512 of 64 s). Wave w: o-block 16w, gathers s rows 16w..+15.
__global__ __launch_bounds__(256) void k_dcn(const ushort* __restrict__ a2t,
    const float* __restrict__ off, const float* __restrict__ off_b,
    const ushort* __restrict__ wt16, float* __restrict__ out) {
  __shared__ __align__(16) ushort smp[64*72];
  int bi = blockIdx.x;
  int b = bi >> 9, tile = bi & 511;
  int s0 = tile << 6;
  int tid = threadIdx.x;
  int lane = tid & 63, wv = tid >> 6;
  int si = lane & 15, rq = lane >> 4, q8 = rq << 3;
  const ushort* a2b = a2t + ((size_t)b << 21);
  const float* offb = off + (((size_t)(b*81)) << 15);
  v4f acc[4];
#pragma unroll
  for (int t = 0; t < 4; t++) acc[t] = (v4f){0.f,0.f,0.f,0.f};
  // coord lanes: lane = (si, rq); s handled by this wave's gather rows
  int s_c = s0 + (wv << 4) + si;
  int zc = s_c >> 10, yc = (s_c >> 5) & 31, xc = s_c & 31;
  for (int k = 0; k < 27; k++) {
    int kz = k/9, ky = (k/3)%3, kx = k%3;
    float pz = (float)(zc + kz - 1) + offb[((size_t)(3*k+0) << 15) + s_c] + off_b[3*k+0];
    float py = (float)(yc + ky - 1) + offb[((size_t)(3*k+1) << 15) + s_c] + off_b[3*k+1];
    float px = (float)(xc + kx - 1) + offb[((size_t)(3*k+2) << 15) + s_c] + off_b[3*k+2];
    float fz = floorf(pz), fy = floorf(py), fx = floorf(px);
    float wz = pz-fz, wy = py-fy, wx = px-fx;
    int z0 = (int)fz, y0 = (int)fy, x0 = (int)fx;
    int dy0 = (rq >> 1) & 1, dx0 = rq & 1;
    int iy = y0 + dy0, ix = x0 + dx0;
    float wyx = (dy0 ? wy : 1.f-wy) * (dx0 ? wx : 1.f-wx);
    bool okyx = (iy >= 0 && iy < 32 && ix >= 0 && ix < 32);
    int cyi = min(max(iy,0),31), cxi = min(max(ix,0),31);
    int iz0 = z0, iz1 = z0 + 1;
    int vidx0 = min(max(iz0,0),31)*1024 + cyi*32 + cxi;
    int vidx1 = min(max(iz1,0),31)*1024 + cyi*32 + cxi;
    float vw0 = (okyx && iz0 >= 0 && iz0 < 32) ? (1.f-wz)*wyx : 0.f;
    float vw1 = (okyx && iz1 >= 0 && iz1 < 32) ? wz*wyx : 0.f;
    int vwb0 = __float_as_int(vw0), vwb1 = __float_as_int(vw1);
    __syncthreads();
    // gather: lane = channel; wave wv fills smp rows 16wv..16wv+15
#pragma unroll
    for (int i = 0; i < 16; i++) {
      float a = 0.f;
#pragma unroll
      for (int r = 0; r < 8; r++) {
        int sl = ((r & 3) << 4) + i;
        int idx = __builtin_amdgcn_readlane(r < 4 ? vidx0 : vidx1, sl);
        int wb  = __builtin_amdgcn_readlane(r < 4 ? vwb0 : vwb1, sl);
        a += __int_as_float(wb) * b2f(a2b[(size_t)idx*64 + lane]);
      }
      smp[((wv<<4)+i)*72 + lane] = f2b(a);
    }
    __syncthreads();
    // MFMA: A from global (L2-hot), o = 16wv + si
    const ushort* wk = wt16 + (k << 12) + (((wv<<4) + si) << 6);
    v8bf af0 = *(const v8bf*)(wk + q8);
    v8bf af1 = *(const v8bf*)(wk + q8 + 32);
#pragma unroll
    for (int t = 0; t < 4; t++) {
      v8bf bf0 = *(const v8bf*)(&smp[((t<<4)+si)*72 + q8]);
      v8bf bf1 = *(const v8bf*)(&smp[((t<<4)+si)*72 + q8 + 32]);
      acc[t] = __builtin_amdgcn_mfma_f32_16x16x32_bf16(af0, bf0, acc[t], 0,0,0);
      acc[t] = __builtin_amdgcn_mfma_f32_16x16x32_bf16(af1, bf1, acc[t], 0,0,0);
    }
  }
#pragma unroll
  for (int t = 0; t < 4; t++)
#pragma unroll
    for (int r = 0; r < 4; r++) {
      int o = (wv << 4) + rq*4 + r;
      out[(((size_t)(b*64 + o)) << 15) + s0 + (t<<4) + si] = acc[t][r];
    }
}

// ---------------- K11: conv1(+dcn_b) -> gate -> proj2 + shortcut ----------
__global__ __launch_bounds__(256) void k_fuse2(const float* __restrict__ dcn,
    const float* __restrict__ dcn_b, const float* __restrict__ c1w,
    const float* __restrict__ c1b, const float* __restrict__ u,
    const float* __restrict__ p2w, const float* __restrict__ p2b,
    const float* __restrict__ x5, float* __restrict__ y2) {
  __shared__ float w1[4096], w2[4096];
  __shared__ float b1[64], b2[64], db[64];
  int gid = blockIdx.x*256 + threadIdx.x;
  for (int i = threadIdx.x; i < 4096; i += 256) { w1[i] = c1w[i]; w2[i] = p2w[i]; }
  if (threadIdx.x < 64) {
    b1[threadIdx.x]=c1b[threadIdx.x]; b2[threadIdx.x]=p2b[threadIdx.x];
    db[threadIdx.x]=dcn_b[threadIdx.x];
  }
  __syncthreads();
  int b = gid >> 15, n = gid & (S-1);
  const float* dbp = dcn + (size_t)b*64*S + n;
  float dv[64];
#pragma unroll
  for (int c = 0; c < 64; c++) dv[c] = dbp[(size_t)c*S] + db[c];
  const float* ub = u + (size_t)b*64*S + n;
  float m[64];
  for (int o = 0; o < 64; o++) {
    float a = b1[o];
#pragma unroll
    for (int c = 0; c < 64; c++) a += w1[o*64+c]*dv[c];
    m[o] = ub[(size_t)o*S] * a;
  }
  const float* sb = x5 + (size_t)b*64*S + n;
  float* yb = y2 + (size_t)b*64*S + n;
  for (int o = 0; o < 64; o++) {
    float a = b2[o];
#pragma unroll
    for (int c = 0; c < 64; c++) a += w2[o*64+c]*m[c];
    yb[(size_t)o*S] = a + sb[(size_t)o*S];
  }
}

// ---------------- K12: reshape-scramble + LN2 + out proj ----------------
__global__ __launch_bounds__(256) void k_final(const float* __restrict__ y2,
    const float* __restrict__ n2w, const float* __restrict__ n2b,
    const float* __restrict__ ow, const float* __restrict__ ob, float* __restrict__ out) {
  __shared__ float wsh[4096];
  __shared__ float nw[64], nb[64], obs[64];
  int bi = blockIdx.x;
  int b = bi >> 7; int mg = (bi >> 4) & 7; int r0 = (bi & 15)*4;
  for (int i = threadIdx.x; i < 4096; i += 256) wsh[i] = ow[i];
  if (threadIdx.x < 64) {
    nw[threadIdx.x]=n2w[threadIdx.x]; nb[threadIdx.x]=n2b[threadIdx.x];
    obs[threadIdx.x]=ob[threadIdx.x];
  }
  __syncthreads();
  int mi = threadIdx.x & 63, rg = threadIdx.x >> 6;
  int r = r0 + rg;
  int m = mg*64 + mi;
  int n = m*64 + r;
  const float* yb = y2 + ((size_t)(b*64+r))*S + m;
  float v[64];
#pragma unroll
  for (int c = 0; c < 64; c++) v[c] = yb[(size_t)c*512];
  float mean = 0.f;
#pragma unroll
  for (int c = 0; c < 64; c++) mean += v[c];
  mean *= (1.0f/64.0f);
  float var = 0.f;
#pragma unroll
  for (int c = 0; c < 64; c++) { float d = v[c]-mean; var += d*d; }
  var *= (1.0f/64.0f);
  float rs = rsqrtf(var + 1e-5f);
#pragma unroll
  for (int c = 0; c < 64; c++) v[c] = (v[c]-mean)*rs*nw[c] + nb[c];
  float* orow = out + ((size_t)b*S + n)*64;
  for (int o4 = 0; o4 < 16; o4++) {
    float4 a;
    float t0=obs[o4*4+0], t1=obs[o4*4+1], t2=obs[o4*4+2], t3=obs[o4*4+3];
#pragma unroll
    for (int c = 0; c < 64; c++) {
      float lv = v[c];
      t0 += wsh[(o4*4+0)*64+c]*lv; t1 += wsh[(o4*4+1)*64+c]*lv;
      t2 += wsh[(o4*4+2)*64+c]*lv; t3 += wsh[(o4*4+3)*64+c]*lv;
    }
    a.x=t0; a.y=t1; a.z=t2; a.w=t3;
    ((float4*)orow)[o4] = a;
  }
}

extern "C" void kernel_launch(void* const* d_in, const int* in_sizes, int n_in,
                              void* d_out, int out_size, void* d_ws, size_t ws_size,
                              hipStream_t stream) {
  const float* x      = (const float*)d_in[0];
  const float* temp   = (const float*)d_in[1];
  const float* qkv_w  = (const float*)d_in[2];
  const float* norm_w = (const float*)d_in[3];
  const float* norm_b = (const float*)d_in[4];
  const float* p1w    = (const float*)d_in[5];
  const float* p1b    = (const float*)d_in[6];
  const float* c0w    = (const float*)d_in[7];
  const float* c0b    = (const float*)d_in[8];
  const float* cspw   = (const float*)d_in[9];
  const float* cspb   = (const float*)d_in[10];
  const float* offw   = (const float*)d_in[11];
  const float* offb   = (const float*)d_in[12];
  const float* dcnw   = (const float*)d_in[13];
  const float* dcnb   = (const float*)d_in[14];
  const float* c1w    = (const float*)d_in[15];
  const float* c1b    = (const float*)d_in[16];
  const float* p2w    = (const float*)d_in[17];
  const float* p2b    = (const float*)d_in[18];
  const float* n2w    = (const float*)d_in[19];
  const float* n2b    = (const float*)d_in[20];
  const float* outw   = (const float*)d_in[21];
  const float* outb   = (const float*)d_in[22];
  float* out = (float*)d_out;

  float* Wa  = (float*)d_ws;                  // q -> x5
  float* Wb  = Wa + BUFN;                     // k -> u
  float* Wc  = Wb + BUFN;                     // a2 -> dcn
  float* OFF = Wc + BUFN;                     // off -> y2
  float* SM  = OFF + (size_t)2*81*S;
  float* SM_inv  = SM;
  float* SM_gram = SM + 256;
  float* SM_attn = SM + 2304;
  ushort* WT_OFF16 = (ushort*)(SM + 4352);    // 27*96*64 = 165888 ushorts
  ushort* WT_DCN16 = WT_OFF16 + 165888;       // 27*64*64 = 110592 ushorts
  float* vbuf = out;                          // d_out scratch: v -> a1 -> a2t -> out
  ushort* a2t = (ushort*)d_out;               // bf16 [B][S][C] after k_tr

  hipMemsetAsync(SM, 0, 4352*sizeof(float), stream);
  k_wt     <<<648, 256, 0, stream>>>(offw, dcnw, WT_OFF16, WT_DCN16);

  k_qkv    <<<512, 256, 0, stream>>>(x, qkv_w, Wa, Wb, vbuf);
  k_rownorm<<<256, 256, 0, stream>>>(Wa, Wb, SM_inv);
  k_gram   <<<256, 256, 0, stream>>>(Wa, Wb, SM_gram);
  k_attnsm <<<1,   128, 0, stream>>>(SM_gram, SM_inv, temp, SM_attn);
  k_xca_ln <<<256, 256, 0, stream>>>(vbuf, SM_attn, norm_w, norm_b, Wa);   // x5 -> Wa
  k_proj1  <<<512, 256, 0, stream>>>(Wa, p1w, p1b, Wb);                    // u -> Wb
  k_conv0  <<<4096,128, 0, stream>>>(Wb, c0w, c0b, vbuf);                  // a1 -> d_out
  k_convsp <<<4096,128, 0, stream>>>(vbuf, cspw, cspb, Wc);                // a2 -> Wc
  k_tr     <<<1024,256, 0, stream>>>(Wc, a2t);                             // a2t -> d_out
  k_offconv<<<1024,256, 0, stream>>>(a2t, WT_OFF16, OFF);
  k_dcn    <<<1024,256, 0, stream>>>(a2t, OFF, offb, WT_DCN16, Wc);        // dcn -> Wc
  k_fuse2  <<<256, 256, 0, stream>>>(Wc, dcnb, c1w, c1b, Wb, p2w, p2b, Wa, OFF); // y2 -> OFF
  k_final  <<<256, 256, 0, stream>>>(OFF, n2w, n2b, outw, outb, out);
}

// Round 5
// 1053.265 us; speedup vs baseline: 4.3165x; 1.0834x over previous
//
#include <hip/hip_runtime.h>
#include <hip/hip_bf16.h>

#define S 32768
#define BUFN (2*64*32768)

typedef __bf16 v8bf __attribute__((ext_vector_type(8)));
typedef float v4f __attribute__((ext_vector_type(4)));
typedef int v4i __attribute__((ext_vector_type(4)));

__device__ __forceinline__ ushort f2b(float f) {
  union { float f; unsigned u; } v; v.f = f;
  unsigned r = (v.u + 0x7fffu + ((v.u >> 16) & 1u)) >> 16;
  return (ushort)r;
}

// ---------------- K0: weight transpose + bf16 (one-off, tiny) ----------------
// wt_off16[t][o<96][c] (o>=81 zero); wt_dcn16[k][o][c]
__global__ void k_wt(const float* __restrict__ offw, const float* __restrict__ dcnw,
                     ushort* __restrict__ wt_off16, ushort* __restrict__ wt_dcn16) {
  int i = blockIdx.x*256 + threadIdx.x;
  if (i < 27*96*64) {
    int c = i & 63, o = (i >> 6) % 96, t = i / 6144;
    wt_off16[i] = (o < 81) ? f2b(offw[o*1728 + c*27 + t]) : (ushort)0;
  }
  if (i < 27*64*64) {
    int c = i & 63, o = (i >> 6) & 63, k = i >> 12;
    wt_dcn16[i] = f2b(dcnw[(o*64 + c)*27 + k]);
  }
}

// ---------------- K1: qkv ----------------
__global__ __launch_bounds__(256) void k_qkv(const float* __restrict__ x,
    const float* __restrict__ qkv_w, float* __restrict__ q,
    float* __restrict__ k, float* __restrict__ v) {
  __shared__ float wsm[96*64];
  int half = blockIdx.x >> 8;
  int gid  = ((blockIdx.x & 255) << 8) + threadIdx.x;
  int rbase = half * 96;
  for (int i = threadIdx.x; i < 96*64; i += 256) wsm[i] = qkv_w[rbase*64 + i];
  __syncthreads();
  int b = gid >> 15, n = gid & (S-1);
  const float* xr = x + (size_t)gid * 64;
  float xv[64];
#pragma unroll
  for (int i = 0; i < 16; i++) {
    float4 t = ((const float4*)xr)[i];
    xv[4*i]=t.x; xv[4*i+1]=t.y; xv[4*i+2]=t.z; xv[4*i+3]=t.w;
  }
  for (int r = 0; r < 96; r++) {
    float acc = 0.f;
#pragma unroll
    for (int c = 0; c < 64; c++) acc += xv[c] * wsm[r*64+c];
    int row = rbase + r;
    float* dst = (row < 64) ? q : (row < 128 ? k : v);
    int ch = row & 63;
    dst[((size_t)(b*64 + ch))*S + n] = acc;
  }
}

// ---------------- K2: per-row inv L2 norm of q,k ----------------
__global__ __launch_bounds__(256) void k_rownorm(const float* __restrict__ q,
    const float* __restrict__ k, float* __restrict__ inv) {
  int row = blockIdx.x;
  const float* p = (row < 128) ? (q + (size_t)row*S) : (k + (size_t)(row-128)*S);
  const float4* p4 = (const float4*)p;
  float ss = 0.f;
  for (int i = threadIdx.x; i < S/4; i += 256) {
    float4 t = p4[i];
    ss += t.x*t.x + t.y*t.y + t.z*t.z + t.w*t.w;
  }
  __shared__ float red[256];
  red[threadIdx.x] = ss; __syncthreads();
  for (int st = 128; st > 0; st >>= 1) {
    if (threadIdx.x < st) red[threadIdx.x] += red[threadIdx.x+st];
    __syncthreads();
  }
  if (threadIdx.x == 0) inv[row] = 1.0f / fmaxf(sqrtf(red[0]), 1e-12f);
}

// ---------------- K3: gram ----------------
__global__ __launch_bounds__(256) void k_gram(const float* __restrict__ q,
    const float* __restrict__ k, float* __restrict__ gram) {
  __shared__ float qt[16][65], kt[16][65];
  int bi = blockIdx.x;
  int b = bi >> 7, h = (bi >> 5) & 3, chunk = bi & 31;
  int c = threadIdx.x >> 4, d = threadIdx.x & 15;
  const float* qb = q + ((size_t)(b*64 + h*16))*S;
  const float* kb = k + ((size_t)(b*64 + h*16))*S;
  int lr = threadIdx.x >> 4, lc = (threadIdx.x & 15) * 4;
  float acc = 0.f;
  for (int n0 = chunk*1024; n0 < chunk*1024 + 1024; n0 += 64) {
    float4 tq = *(const float4*)(qb + (size_t)lr*S + n0 + lc);
    float4 tk = *(const float4*)(kb + (size_t)lr*S + n0 + lc);
    __syncthreads();
    qt[lr][lc]=tq.x; qt[lr][lc+1]=tq.y; qt[lr][lc+2]=tq.z; qt[lr][lc+3]=tq.w;
    kt[lr][lc]=tk.x; kt[lr][lc+1]=tk.y; kt[lr][lc+2]=tk.z; kt[lr][lc+3]=tk.w;
    __syncthreads();
#pragma unroll
    for (int nn = 0; nn < 64; nn++) acc += qt[c][nn]*kt[d][nn];
  }
  atomicAdd(&gram[((b*4+h)*16+c)*16 + d], acc);
}

// ---------------- K4: softmax ----------------
__global__ void k_attnsm(const float* __restrict__ gram, const float* __restrict__ inv,
    const float* __restrict__ temp, float* __restrict__ attn) {
  int t = threadIdx.x; if (t >= 128) return;
  int b = t >> 6, h = (t >> 4) & 3, c = t & 15;
  float iq = inv[b*64 + h*16 + c];
  float tp = temp[h];
  float l[16], m = -1e30f;
#pragma unroll
  for (int d = 0; d < 16; d++) {
    float vv = gram[((b*4+h)*16+c)*16 + d] * iq * inv[128 + b*64 + h*16 + d] * tp;
    l[d] = vv; m = fmaxf(m, vv);
  }
  float s = 0.f;
#pragma unroll
  for (int d = 0; d < 16; d++) { l[d] = expf(l[d]-m); s += l[d]; }
  float is = 1.0f / s;
#pragma unroll
  for (int d = 0; d < 16; d++) attn[((b*4+h)*16+c)*16 + d] = l[d]*is;
}

// ---------------- K5: x_ca = attn@v, layernorm, store x5 ----------------
__global__ __launch_bounds__(256) void k_xca_ln(const float* __restrict__ v,
    const float* __restrict__ attn, const float* __restrict__ nw,
    const float* __restrict__ nb, float* __restrict__ x5) {
  __shared__ float at[1024];
  __shared__ float wsh[64], bsh[64];
  int gid = blockIdx.x*256 + threadIdx.x;
  int b = gid >> 15, n = gid & (S-1);
  for (int i = threadIdx.x; i < 1024; i += 256) at[i] = attn[b*1024 + i];
  if (threadIdx.x < 64) { wsh[threadIdx.x]=nw[threadIdx.x]; bsh[threadIdx.x]=nb[threadIdx.x]; }
  __syncthreads();
  const float* vb = v + (size_t)b*64*S + n;
  float vv[64];
#pragma unroll
  for (int ch = 0; ch < 64; ch++) vv[ch] = vb[(size_t)ch*S];
  float xc[64];
#pragma unroll
  for (int h = 0; h < 4; h++)
#pragma unroll
    for (int cc = 0; cc < 16; cc++) {
      float a = 0.f;
#pragma unroll
      for (int d = 0; d < 16; d++) a += at[(h*16+cc)*16 + d] * vv[h*16+d];
      xc[h*16+cc] = a;
    }
  float mean = 0.f;
#pragma unroll
  for (int ch = 0; ch < 64; ch++) mean += xc[ch];
  mean *= (1.0f/64.0f);
  float var = 0.f;
#pragma unroll
  for (int ch = 0; ch < 64; ch++) { float d = xc[ch]-mean; var += d*d; }
  var *= (1.0f/64.0f);
  float rs = rsqrtf(var + 1e-5f);
  float* xb = x5 + (size_t)b*64*S + n;
#pragma unroll
  for (int ch = 0; ch < 64; ch++)
    xb[(size_t)ch*S] = (xc[ch]-mean)*rs*wsh[ch] + bsh[ch];
}

// ---------------- K6: proj1 + GELU ----------------
__global__ __launch_bounds__(256) void k_proj1(const float* __restrict__ x5,
    const float* __restrict__ w, const float* __restrict__ bias, float* __restrict__ u) {
  __shared__ float wsm[32*64];
  __shared__ float bsm[32];
  int half = blockIdx.x >> 8;
  int gid = ((blockIdx.x & 255) << 8) + threadIdx.x;
  int o0 = half*32;
  for (int i = threadIdx.x; i < 32*64; i += 256) wsm[i] = w[o0*64 + i];
  if (threadIdx.x < 32) bsm[threadIdx.x] = bias[o0 + threadIdx.x];
  __syncthreads();
  int b = gid >> 15, n = gid & (S-1);
  const float* xb = x5 + (size_t)b*64*S + n;
  float xv[64];
#pragma unroll
  for (int ch = 0; ch < 64; ch++) xv[ch] = xb[(size_t)ch*S];
  float* ub = u + (size_t)b*64*S + n;
  for (int oo = 0; oo < 32; oo++) {
    float acc = bsm[oo];
#pragma unroll
    for (int c = 0; c < 64; c++) acc += wsm[oo*64+c]*xv[c];
    float g = 0.5f*acc*(1.0f + erff(acc*0.70710678118654752f));
    ub[(size_t)(o0+oo)*S] = g;
  }
}

// ---------------- K7: depthwise 5^3 pad 2, register-row ILP ----------------
__global__ __launch_bounds__(128) void k_conv0(const float* __restrict__ in,
    const float* __restrict__ w, const float* __restrict__ bias, float* __restrict__ out) {
  __shared__ float tile[5*32*36];
  __shared__ float wsh[125];
  int bi = blockIdx.x;
  int z = bi & 31, c = (bi >> 5) & 63, b = bi >> 11;
  const float* ib = in + ((size_t)(b*64+c) << 15);
  for (int i = threadIdx.x; i < 5*32*36/4; i += 128)
    ((float4*)tile)[i] = make_float4(0.f,0.f,0.f,0.f);
  if (threadIdx.x < 125) wsh[threadIdx.x] = w[c*125 + threadIdx.x];
  __syncthreads();
  for (int i = threadIdx.x; i < 5*1024; i += 128) {
    int dz = i >> 10, r = i & 1023;
    int zg = z + dz - 2;
    if (zg >= 0 && zg < 32)
      tile[(dz*32 + (r >> 5))*36 + (r & 31) + 2] = ib[zg*1024 + r];
  }
  __syncthreads();
  int y = threadIdx.x >> 2, x0 = (threadIdx.x & 3) << 3;
  float bv = bias[c];
  float acc[8];
#pragma unroll
  for (int j = 0; j < 8; j++) acc[j] = bv;
  for (int dz = 0; dz < 5; dz++) {
#pragma unroll
    for (int dy = 0; dy < 5; dy++) {
      int yy = y + dy - 2;
      if (yy < 0 || yy >= 32) continue;
      const float* wp = &wsh[(dz*5+dy)*5];
      float wreg[5];
#pragma unroll
      for (int dx = 0; dx < 5; dx++) wreg[dx] = wp[dx];
      const float* rp = &tile[(dz*32+yy)*36 + x0];
      float4 r0 = ((const float4*)rp)[0];
      float4 r1 = ((const float4*)rp)[1];
      float4 r2 = ((const float4*)rp)[2];
      float row[12] = {r0.x,r0.y,r0.z,r0.w, r1.x,r1.y,r1.z,r1.w, r2.x,r2.y,r2.z,r2.w};
#pragma unroll
      for (int dx = 0; dx < 5; dx++)
#pragma unroll
        for (int j = 0; j < 8; j++)
          acc[j] += wreg[dx] * row[dx+j];
    }
  }
  float* ob = out + ((size_t)(b*64+c) << 15) + z*1024 + y*32 + x0;
  float4 s0; s0.x=acc[0]; s0.y=acc[1]; s0.z=acc[2]; s0.w=acc[3];
  float4 s1; s1.x=acc[4]; s1.y=acc[5]; s1.z=acc[6]; s1.w=acc[7];
  ((float4*)ob)[0] = s0; ((float4*)ob)[1] = s1;
}

// ---------------- K8: depthwise 7^3 dil 3 pad 9, register-row ILP ----------------
__global__ __launch_bounds__(128) void k_convsp(const float* __restrict__ in,
    const float* __restrict__ w, const float* __restrict__ bias, float* __restrict__ out) {
  __shared__ float tile[7*32*52];
  __shared__ float wsh[344];
  int bi = blockIdx.x;
  int z = bi & 31, c = (bi >> 5) & 63, b = bi >> 11;
  const float* ib = in + ((size_t)(b*64+c) << 15);
  for (int i = threadIdx.x; i < 7*32*52/4; i += 128)
    ((float4*)tile)[i] = make_float4(0.f,0.f,0.f,0.f);
  for (int i = threadIdx.x; i < 343; i += 128) wsh[i] = w[c*343 + i];
  __syncthreads();
  for (int i = threadIdx.x; i < 7*1024; i += 128) {
    int t = i >> 10, r = i & 1023;
    int zg = z + 3*t - 9;
    if (zg >= 0 && zg < 32)
      tile[(t*32 + (r >> 5))*52 + (r & 31) + 9] = ib[zg*1024 + r];
  }
  __syncthreads();
  int y = threadIdx.x >> 2, x0 = (threadIdx.x & 3) << 3;
  float bv = bias[c];
  float acc[8];
#pragma unroll
  for (int j = 0; j < 8; j++) acc[j] = bv;
  for (int t = 0; t < 7; t++) {
#pragma unroll
    for (int dy = 0; dy < 7; dy++) {
      int yy = y + 3*dy - 9;
      if (yy < 0 || yy >= 32) continue;
      const float* wp = &wsh[(t*7+dy)*7];
      float wreg[7];
#pragma unroll
      for (int dx = 0; dx < 7; dx++) wreg[dx] = wp[dx];
      const float* rp = &tile[(t*32+yy)*52 + x0];
      float4 r0 = ((const float4*)rp)[0];
      float4 r1 = ((const float4*)rp)[1];
      float4 r2 = ((const float4*)rp)[2];
      float4 r3 = ((const float4*)rp)[3];
      float4 r4 = ((const float4*)rp)[4];
      float4 r5 = ((const float4*)rp)[5];
      float4 r6 = ((const float4*)rp)[6];
      float row[28] = {r0.x,r0.y,r0.z,r0.w, r1.x,r1.y,r1.z,r1.w,
                       r2.x,r2.y,r2.z,r2.w, r3.x,r3.y,r3.z,r3.w,
                       r4.x,r4.y,r4.z,r4.w, r5.x,r5.y,r5.z,r5.w,
                       r6.x,r6.y,r6.z,r6.w};
#pragma unroll
      for (int dx = 0; dx < 7; dx++)
#pragma unroll
        for (int j = 0; j < 8; j++)
          acc[j] += wreg[dx] * row[3*dx+j];
    }
  }
  float* ob = out + ((size_t)(b*64+c) << 15) + z*1024 + y*32 + x0;
  float4 s0; s0.x=acc[0]; s0.y=acc[1]; s0.z=acc[2]; s0.w=acc[3];
  float4 s1; s1.x=acc[4]; s1.y=acc[5]; s1.z=acc[6]; s1.w=acc[7];
  ((float4*)ob)[0] = s0; ((float4*)ob)[1] = s1;
}

// ---------------- K8b: transpose a2 [C][S] f32 -> a2t [S][C] bf16 ----------------
__global__ __launch_bounds__(256) void k_tr(const float* __restrict__ a2,
                                            ushort* __restrict__ a2t) {
  __shared__ float tile[64*65];
  int bi = blockIdx.x;
  int b = bi >> 9, chunk = bi & 511;
  int s0 = chunk << 6;
  const float* ib = a2 + ((size_t)b << 21) + s0;
#pragma unroll
  for (int i = 0; i < 16; i++) {
    int j = threadIdx.x + (i << 8);
    int c = j >> 6, sl = j & 63;
    tile[c*65 + sl] = ib[((size_t)c << 15) + sl];
  }
  __syncthreads();
  ushort* ob = a2t + ((size_t)b << 21) + ((size_t)s0 << 6);
#pragma unroll
  for (int i = 0; i < 16; i++) {
    int j = threadIdx.x + (i << 8);
    int sl = j >> 6, c = j & 63;
    ob[sl*64 + c] = f2b(tile[c*65 + sl]);
  }
}

// ---------------- K9 v4: offset conv, LDS-free barrier-free MFMA ----------------
// Grid 1024 = b(2)*stile(512 of 64 s). Wave wv owns 16 s; 6 o-tiles (96 o padded).
// B-frag loaded directly from a2t (shifted row, masked); A-frag from wt16 (L1-hot).
__global__ __launch_bounds__(256) void k_offconv(const ushort* __restrict__ a2t,
    const ushort* __restrict__ wt16, float* __restrict__ off) {
  int bi = blockIdx.x;
  int b = bi >> 9, tile = bi & 511;
  int s0 = tile << 6;
  int tid = threadIdx.x;
  int lane = tid & 63, wv = tid >> 6;
  int si = lane & 15, rq = lane >> 4, q8 = rq << 3;
  int sw = s0 + (wv << 4);
  int s_c = sw + si;
  int zc = s_c >> 10, yc = (s_c >> 5) & 31, xc = s_c & 31;
  const ushort* a2b = a2t + ((size_t)b << 21);
  v4f acc[6];
#pragma unroll
  for (int i = 0; i < 6; i++) acc[i] = (v4f){0.f,0.f,0.f,0.f};
  const v4i z4 = {0,0,0,0};
  for (int t = 0; t < 27; t++) {
    int kz = t/9, ky = (t/3)%3, kx = t%3;
    int zz = zc + kz - 1, yy = yc + ky - 1, xx = xc + kx - 1;
    bool ok = (zz>=0 && zz<32 && yy>=0 && yy<32 && xx>=0 && xx<32);
    v8bf b0 = __builtin_bit_cast(v8bf, z4);
    v8bf b1 = __builtin_bit_cast(v8bf, z4);
    if (ok) {
      const ushort* p = a2b + ((size_t)((zz<<10)+(yy<<5)+xx) << 6) + q8;
      b0 = *(const v8bf*)p;
      b1 = *(const v8bf*)(p + 32);
    }
    const ushort* wk = wt16 + t*6144;
#pragma unroll
    for (int ot = 0; ot < 6; ot++) {
      const ushort* ap = wk + (((ot<<4) + si) << 6) + q8;
      v8bf a0 = *(const v8bf*)ap;
      v8bf a1 = *(const v8bf*)(ap + 32);
      acc[ot] = __builtin_amdgcn_mfma_f32_16x16x32_bf16(a0, b0, acc[ot], 0,0,0);
      acc[ot] = __builtin_amdgcn_mfma_f32_16x16x32_bf16(a1, b1, acc[ot], 0,0,0);
    }
  }
#pragma unroll
  for (int ot = 0; ot < 6; ot++)
#pragma unroll
    for (int r = 0; r < 4; r++) {
      int o = ot*16 + rq*4 + r;
      if (o < 81)
        off[(((size_t)(b*81 + o)) << 15) + sw + si] = acc[ot][r];
    }
}

// ---------------- K10 v4: deformable conv, register-resident gather + MFMA ------
// Grid 1024 = b(2)*stile(512 of 64 s). Wave wv owns 16 s; each lane (si,rq) builds
// its own B-fragment (8 corners x b128 loads, fp32 combine), then 4 o-tile MFMAs.
// No LDS, no barriers, no readlanes.
__global__ __launch_bounds__(256) void k_dcn(const ushort* __restrict__ a2t,
    const float* __restrict__ off, const float* __restrict__ off_b,
    const ushort* __restrict__ wt16, float* __restrict__ out) {
  int bi = blockIdx.x;
  int b = bi >> 9, tile = bi & 511;
  int s0 = tile << 6;
  int tid = threadIdx.x;
  int lane = tid & 63, wv = tid >> 6;
  int si = lane & 15, rq = lane >> 4, q8 = rq << 3;
  int sw = s0 + (wv << 4);
  int s_c = sw + si;
  int zc = s_c >> 10, yc = (s_c >> 5) & 31, xc = s_c & 31;
  const ushort* a2b = a2t + ((size_t)b << 21);
  const float* offb = off + (((size_t)(b*81)) << 15);
  v4f acc[4];
#pragma unroll
  for (int t = 0; t < 4; t++) acc[t] = (v4f){0.f,0.f,0.f,0.f};
  for (int k = 0; k < 27; k++) {
    int kz = k/9, ky = (k/3)%3, kx = k%3;
    float pz = (float)(zc + kz - 1) + offb[((size_t)(3*k+0) << 15) + s_c] + off_b[3*k+0];
    float py = (float)(yc + ky - 1) + offb[((size_t)(3*k+1) << 15) + s_c] + off_b[3*k+1];
    float px = (float)(xc + kx - 1) + offb[((size_t)(3*k+2) << 15) + s_c] + off_b[3*k+2];
    float fz = floorf(pz), fy = floorf(py), fx = floorf(px);
    float wz = pz-fz, wy = py-fy, wx = px-fx;
    int z0 = (int)fz, y0 = (int)fy, x0 = (int)fx;
    int zi[2], yi[2], xi[2];
    float zw[2], yw[2], xw[2];
#pragma unroll
    for (int d = 0; d < 2; d++) {
      int iz = z0 + d;
      zi[d] = min(max(iz,0),31) << 10;
      zw[d] = (iz >= 0 && iz < 32) ? (d ? wz : 1.f-wz) : 0.f;
      int iy = y0 + d;
      yi[d] = min(max(iy,0),31) << 5;
      yw[d] = (iy >= 0 && iy < 32) ? (d ? wy : 1.f-wy) : 0.f;
      int ix = x0 + d;
      xi[d] = min(max(ix,0),31);
      xw[d] = (ix >= 0 && ix < 32) ? (d ? wx : 1.f-wx) : 0.f;
    }
    float fa[16];
#pragma unroll
    for (int j = 0; j < 16; j++) fa[j] = 0.f;
#pragma unroll
    for (int r = 0; r < 8; r++) {
      int dz = r >> 2, dy = (r >> 1) & 1, dx = r & 1;
      int idx = zi[dz] + yi[dy] + xi[dx];
      float w = zw[dz] * yw[dy] * xw[dx];
      const ushort* p = a2b + ((size_t)idx << 6) + q8;
      v4i lo = *(const v4i*)p;
      v4i hi = *(const v4i*)(p + 32);
#pragma unroll
      for (int m = 0; m < 4; m++) {
        unsigned dvl = (unsigned)lo[m];
        fa[2*m]     += w * __uint_as_float(dvl << 16);
        fa[2*m+1]   += w * __uint_as_float(dvl & 0xffff0000u);
        unsigned dvh = (unsigned)hi[m];
        fa[8+2*m]   += w * __uint_as_float(dvh << 16);
        fa[8+2*m+1] += w * __uint_as_float(dvh & 0xffff0000u);
      }
    }
    // pack fa[0..15] -> two bf16x8 fragments (round-half-up)
    v4i d0, d1;
#pragma unroll
    for (int m = 0; m < 4; m++) {
      unsigned l0 = (__float_as_uint(fa[2*m])   + 0x8000u) >> 16;
      unsigned h0 = (__float_as_uint(fa[2*m+1]) + 0x8000u) & 0xffff0000u;
      d0[m] = (int)(l0 | h0);
      unsigned l1 = (__float_as_uint(fa[8+2*m])   + 0x8000u) >> 16;
      unsigned h1 = (__float_as_uint(fa[8+2*m+1]) + 0x8000u) & 0xffff0000u;
      d1[m] = (int)(l1 | h1);
    }
    v8bf bf0 = __builtin_bit_cast(v8bf, d0);
    v8bf bf1 = __builtin_bit_cast(v8bf, d1);
    const ushort* wk = wt16 + (k << 12);
#pragma unroll
    for (int ot = 0; ot < 4; ot++) {
      const ushort* ap = wk + (((ot<<4) + si) << 6) + q8;
      v8bf a0 = *(const v8bf*)ap;
      v8bf a1 = *(const v8bf*)(ap + 32);
      acc[ot] = __builtin_amdgcn_mfma_f32_16x16x32_bf16(a0, bf0, acc[ot], 0,0,0);
      acc[ot] = __builtin_amdgcn_mfma_f32_16x16x32_bf16(a1, bf1, acc[ot], 0,0,0);
    }
  }
#pragma unroll
  for (int ot = 0; ot < 4; ot++)
#pragma unroll
    for (int r = 0; r < 4; r++) {
      int o = (ot << 4) + rq*4 + r;
      out[(((size_t)(b*64 + o)) << 15) + sw + si] = acc[ot][r];
    }
}

// ---------------- K11: conv1(+dcn_b) -> gate -> proj2 + shortcut ----------
__global__ __launch_bounds__(256) void k_fuse2(const float* __restrict__ dcn,
    const float* __restrict__ dcn_b, const float* __restrict__ c1w,
    const float* __restrict__ c1b, const float* __restrict__ u,
    const float* __restrict__ p2w, const float* __restrict__ p2b,
    const float* __restrict__ x5, float* __restrict__ y2) {
  __shared__ float w1[4096], w2[4096];
  __shared__ float b1[64], b2[64], db[64];
  int gid = blockIdx.x*256 + threadIdx.x;
  for (int i = threadIdx.x; i < 4096; i += 256) { w1[i] = c1w[i]; w2[i] = p2w[i]; }
  if (threadIdx.x < 64) {
    b1[threadIdx.x]=c1b[threadIdx.x]; b2[threadIdx.x]=p2b[threadIdx.x];
    db[threadIdx.x]=dcn_b[threadIdx.x];
  }
  __syncthreads();
  int b = gid >> 15, n = gid & (S-1);
  const float* dbp = dcn + (size_t)b*64*S + n;
  float dv[64];
#pragma unroll
  for (int c = 0; c < 64; c++) dv[c] = dbp[(size_t)c*S] + db[c];
  const float* ub = u + (size_t)b*64*S + n;
  float m[64];
  for (int o = 0; o < 64; o++) {
    float a = b1[o];
#pragma unroll
    for (int c = 0; c < 64; c++) a += w1[o*64+c]*dv[c];
    m[o] = ub[(size_t)o*S] * a;
  }
  const float* sb = x5 + (size_t)b*64*S + n;
  float* yb = y2 + (size_t)b*64*S + n;
  for (int o = 0; o < 64; o++) {
    float a = b2[o];
#pragma unroll
    for (int c = 0; c < 64; c++) a += w2[o*64+c]*m[c];
    yb[(size_t)o*S] = a + sb[(size_t)o*S];
  }
}

// ---------------- K12: reshape-scramble + LN2 + out proj ----------------
__global__ __launch_bounds__(256) void k_final(const float* __restrict__ y2,
    const float* __restrict__ n2w, const float* __restrict__ n2b,
    const float* __restrict__ ow, const float* __restrict__ ob, float* __restrict__ out) {
  __shared__ float wsh[4096];
  __shared__ float nw[64], nb[64], obs[64];
  int bi = blockIdx.x;
  int b = bi >> 7; int mg = (bi >> 4) & 7; int r0 = (bi & 15)*4;
  for (int i = threadIdx.x; i < 4096; i += 256) wsh[i] = ow[i];
  if (threadIdx.x < 64) {
    nw[threadIdx.x]=n2w[threadIdx.x]; nb[threadIdx.x]=n2b[threadIdx.x];
    obs[threadIdx.x]=ob[threadIdx.x];
  }
  __syncthreads();
  int mi = threadIdx.x & 63, rg = threadIdx.x >> 6;
  int r = r0 + rg;
  int m = mg*64 + mi;
  int n = m*64 + r;
  const float* yb = y2 + ((size_t)(b*64+r))*S + m;
  float v[64];
#pragma unroll
  for (int c = 0; c < 64; c++) v[c] = yb[(size_t)c*512];
  float mean = 0.f;
#pragma unroll
  for (int c = 0; c < 64; c++) mean += v[c];
  mean *= (1.0f/64.0f);
  float var = 0.f;
#pragma unroll
  for (int c = 0; c < 64; c++) { float d = v[c]-mean; var += d*d; }
  var *= (1.0f/64.0f);
  float rs = rsqrtf(var + 1e-5f);
#pragma unroll
  for (int c = 0; c < 64; c++) v[c] = (v[c]-mean)*rs*nw[c] + nb[c];
  float* orow = out + ((size_t)b*S + n)*64;
  for (int o4 = 0; o4 < 16; o4++) {
    float4 a;
    float t0=obs[o4*4+0], t1=obs[o4*4+1], t2=obs[o4*4+2], t3=obs[o4*4+3];
#pragma unroll
    for (int c = 0; c < 64; c++) {
      float lv = v[c];
      t0 += wsh[(o4*4+0)*64+c]*lv; t1 += wsh[(o4*4+1)*64+c]*lv;
      t2 += wsh[(o4*4+2)*64+c]*lv; t3 += wsh[(o4*4+3)*64+c]*lv;
    }
    a.x=t0; a.y=t1; a.z=t2; a.w=t3;
    ((float4*)orow)[o4] = a;
  }
}

extern "C" void kernel_launch(void* const* d_in, const int* in_sizes, int n_in,
                              void* d_out, int out_size, void* d_ws, size_t ws_size,
                              hipStream_t stream) {
  const float* x      = (const float*)d_in[0];
  const float* temp   = (const float*)d_in[1];
  const float* qkv_w  = (const float*)d_in[2];
  const float* norm_w = (const float*)d_in[3];
  const float* norm_b = (const float*)d_in[4];
  const float* p1w    = (const float*)d_in[5];
  const float* p1b    = (const float*)d_in[6];
  const float* c0w    = (const float*)d_in[7];
  const float* c0b    = (const float*)d_in[8];
  const float* cspw   = (const float*)d_in[9];
  const float* cspb   = (const float*)d_in[10];
  const float* offw   = (const float*)d_in[11];
  const float* offb   = (const float*)d_in[12];
  const float* dcnw   = (const float*)d_in[13];
  const float* dcnb   = (const float*)d_in[14];
  const float* c1w    = (const float*)d_in[15];
  const float* c1b    = (const float*)d_in[16];
  const float* p2w    = (const float*)d_in[17];
  const float* p2b    = (const float*)d_in[18];
  const float* n2w    = (const float*)d_in[19];
  const float* n2b    = (const float*)d_in[20];
  const float* outw   = (const float*)d_in[21];
  const float* outb   = (const float*)d_in[22];
  float* out = (float*)d_out;

  float* Wa  = (float*)d_ws;                  // q -> x5
  float* Wb  = Wa + BUFN;                     // k -> u
  float* Wc  = Wb + BUFN;                     // a2 -> dcn
  float* OFF = Wc + BUFN;                     // off -> y2
  float* SM  = OFF + (size_t)2*81*S;
  float* SM_inv  = SM;
  float* SM_gram = SM + 256;
  float* SM_attn = SM + 2304;
  ushort* WT_OFF16 = (ushort*)(SM + 4352);    // 27*96*64 = 165888 ushorts
  ushort* WT_DCN16 = WT_OFF16 + 165888;       // 27*64*64 = 110592 ushorts
  float* vbuf = out;                          // d_out scratch: v -> a1 -> a2t -> out
  ushort* a2t = (ushort*)d_out;               // bf16 [B][S][C] after k_tr

  hipMemsetAsync(SM, 0, 4352*sizeof(float), stream);
  k_wt     <<<648, 256, 0, stream>>>(offw, dcnw, WT_OFF16, WT_DCN16);

  k_qkv    <<<512, 256, 0, stream>>>(x, qkv_w, Wa, Wb, vbuf);
  k_rownorm<<<256, 256, 0, stream>>>(Wa, Wb, SM_inv);
  k_gram   <<<256, 256, 0, stream>>>(Wa, Wb, SM_gram);
  k_attnsm <<<1,   128, 0, stream>>>(SM_gram, SM_inv, temp, SM_attn);
  k_xca_ln <<<256, 256, 0, stream>>>(vbuf, SM_attn, norm_w, norm_b, Wa);   // x5 -> Wa
  k_proj1  <<<512, 256, 0, stream>>>(Wa, p1w, p1b, Wb);                    // u -> Wb
  k_conv0  <<<4096,128, 0, stream>>>(Wb, c0w, c0b, vbuf);                  // a1 -> d_out
  k_convsp <<<4096,128, 0, stream>>>(vbuf, cspw, cspb, Wc);                // a2 -> Wc
  k_tr     <<<1024,256, 0, stream>>>(Wc, a2t);                             // a2t -> d_out
  k_offconv<<<1024,256, 0, stream>>>(a2t, WT_OFF16, OFF);
  k_dcn    <<<1024,256, 0, stream>>>(a2t, OFF, offb, WT_DCN16, Wc);        // dcn -> Wc
  k_fuse2  <<<256, 256, 0, stream>>>(Wc, dcnb, c1w, c1b, Wb, p2w, p2b, Wa, OFF); // y2 -> OFF
  k_final  <<<256, 256, 0, stream>>>(OFF, n2w, n2b, outw, outb, out);
}